// Round 21
// baseline (270.752 us; speedup 1.0000x reference)
//
#include <hip/hip_runtime.h>

typedef unsigned short u16;
typedef __attribute__((ext_vector_type(8))) short short8;
typedef __attribute__((ext_vector_type(4))) float f32x4;

#define DEVI __device__ __forceinline__

static constexpr int Nn = 1024;   // sequence length
static constexpr int Cc = 1024;   // channels

DEVI u16 f2bf(float f) {
  union { float f; unsigned u; } v; v.f = f;
  unsigned r = v.u + 0x7fffu + ((v.u >> 16) & 1u);
  return (u16)(r >> 16);
}

DEVI void async_ld16(const void* g, void* lds) {
  __builtin_amdgcn_global_load_lds(
      (__attribute__((address_space(1))) void*)g,
      (__attribute__((address_space(3))) void*)lds, 16, 0, 0);
}

// ---------------- fused fp32 -> bf16 weight convert (skips unused apw) ----
__global__ __launch_bounds__(256) void cvt_all(
    const float* __restrict__ s0, const float* __restrict__ s2,
    const float* __restrict__ s3, const float* __restrict__ s4,
    u16* __restrict__ out) {
  const size_t j = ((size_t)blockIdx.x * 256 + threadIdx.x) * 4;
  size_t i; const float* src; size_t lo;
  if (j < 3145728) { i = j; src = s0; lo = 0; }
  else {
    i = j + 1048576;
    if (i < 5242880)      { src = s2; lo = 4194304; }
    else if (i < 9437184) { src = s3; lo = 5242880; }
    else                  { src = s4; lo = 9437184; }
  }
  const float4 v = *(const float4*)&src[i - lo];
  ushort4 o;
  o.x = f2bf(v.x); o.y = f2bf(v.y); o.z = f2bf(v.z); o.w = f2bf(v.w);
  *(ushort4*)&out[i] = o;
}

// ---------------- transpose 1024x1024 fp32 -> bf16 (out[j,i] = in[i,j]) ----
__global__ __launch_bounds__(256) void transpose_wT(const float* __restrict__ in,
                                                    u16* __restrict__ out) {
  __shared__ u16 tile[64][72];
  const int bx = blockIdx.x & 15, by = blockIdx.x >> 4;
  const int tr = threadIdx.x >> 2;
  const int tc4 = (threadIdx.x & 3) * 16;
#pragma unroll
  for (int j = 0; j < 4; ++j) {
    const float4 v = *(const float4*)&in[(size_t)(by * 64 + tr) * 1024 +
                                         bx * 64 + tc4 + j * 4];
    tile[tc4 + j * 4 + 0][tr] = f2bf(v.x);
    tile[tc4 + j * 4 + 1][tr] = f2bf(v.y);
    tile[tc4 + j * 4 + 2][tr] = f2bf(v.z);
    tile[tc4 + j * 4 + 3][tr] = f2bf(v.w);
  }
  __syncthreads();
#pragma unroll
  for (int j = 0; j < 4; ++j) {
    ushort4 o;
    o.x = tile[tr][tc4 + j * 4 + 0];
    o.y = tile[tr][tc4 + j * 4 + 1];
    o.z = tile[tr][tc4 + j * 4 + 2];
    o.w = tile[tr][tc4 + j * 4 + 3];
    *(ushort4*)&out[(size_t)(bx * 64 + tr) * 1024 + by * 64 + tc4 + j * 4] = o;
  }
}

// ---------------- combined bias: cb[j] = bpb[j] + dot(apb, bpw_row_j) ------
__global__ __launch_bounds__(256) void cbias_k(const float* __restrict__ apb,
                                               const float* __restrict__ bpw,
                                               const float* __restrict__ bpb,
                                               float* __restrict__ cb) {
  const int j = blockIdx.x * 4 + (threadIdx.x >> 6);
  const int lane = threadIdx.x & 63;
  float s = 0.f;
  for (int k = lane; k < 1024; k += 64) s += apb[k] * bpw[(size_t)j * 1024 + k];
#pragma unroll
  for (int m = 1; m < 64; m <<= 1) s += __shfl_xor(s, m);
  if (lane == 0) cb[j] = s + bpb[j];
}

// ---------------- GEMM 64x64 tile (for the 1024^3 Wc precompute) ----------
__global__ __launch_bounds__(256) void gemm64(const u16* __restrict__ A,
                                              const u16* __restrict__ W,
                                              u16* __restrict__ out, int K) {
  __shared__ __align__(16) u16 As[64 * 64];
  __shared__ __align__(16) u16 Bs[64 * 64];
  const int tid = threadIdx.x;
  const int wave = tid >> 6, lane = tid & 63;
  const int g = lane >> 4, lr = lane & 15;
  const int brow = (blockIdx.x >> 4) << 6, bcol = (blockIdx.x & 15) << 6;
  const int srow = lane >> 3;
  const int scg = (lane & 7) ^ srow;
  const int swz = (lr & 7) << 4;

  f32x4 acc[4];
#pragma unroll
  for (int j = 0; j < 4; ++j) acc[j] = (f32x4){0.f, 0.f, 0.f, 0.f};

  for (int k0 = 0; k0 < K; k0 += 64) {
#pragma unroll
    for (int u = 0; u < 2; ++u) {
      async_ld16(A + (size_t)(brow + u * 32 + wave * 8 + srow) * K + k0 + scg * 8,
                 (char*)As + u * 4096 + wave * 1024);
      async_ld16(W + (size_t)(bcol + u * 32 + wave * 8 + srow) * K + k0 + scg * 8,
                 (char*)Bs + u * 4096 + wave * 1024);
    }
    __syncthreads();
    short8 af[2], bf[4][2];
#pragma unroll
    for (int kk = 0; kk < 2; ++kk)
      af[kk] = *(const short8*)((char*)As + (wave * 16 + lr) * 128 +
                                ((kk * 64 + g * 16) ^ swz));
#pragma unroll
    for (int nf = 0; nf < 4; ++nf)
#pragma unroll
      for (int kk = 0; kk < 2; ++kk)
        bf[nf][kk] = *(const short8*)((char*)Bs + (nf * 16 + lr) * 128 +
                                      ((kk * 64 + g * 16) ^ swz));
#pragma unroll
    for (int kk = 0; kk < 2; ++kk)
#pragma unroll
      for (int nf = 0; nf < 4; ++nf)
        acc[nf] = __builtin_amdgcn_mfma_f32_16x16x32_bf16(af[kk], bf[nf][kk],
                                                          acc[nf], 0, 0, 0);
    __syncthreads();
  }
#pragma unroll
  for (int nf = 0; nf < 4; ++nf)
#pragma unroll
    for (int reg = 0; reg < 4; ++reg)
      out[(size_t)(brow + wave * 16 + g * 4 + reg) * 1024 +
          bcol + nf * 16 + lr] = f2bf(acc[nf][reg]);
}

// ---------------- V transpose: qkv V-part -> vt[b,h][d][t] bf16 -----------
__global__ __launch_bounds__(256) void vtrans(const u16* __restrict__ qkv,
                                              u16* __restrict__ vt) {
  __shared__ u16 tile[64][72];
  const int bh = blockIdx.x >> 4, tb = blockIdx.x & 15;
  const int b = bh >> 4, h = bh & 15;
  const int t0 = tb * 64;
  const int tid = threadIdx.x;
  const int rr = tid >> 3, c8 = (tid & 7) * 8;
#pragma unroll
  for (int r = 0; r < 2; ++r) {
    const int t = r * 32 + rr;
    const short8 v = *(const short8*)(qkv + (size_t)(b * Nn + t0 + t) * 3072 +
                                      2048 + h * 64 + c8);
#pragma unroll
    for (int j = 0; j < 8; ++j) tile[t][c8 + j] = (u16)v[j];
  }
  __syncthreads();
#pragma unroll
  for (int r = 0; r < 2; ++r) {
    const int d = r * 32 + rr;
    short8 o;
#pragma unroll
    for (int j = 0; j < 8; ++j) o[j] = (short)tile[c8 + j][d];
    *(short8*)(vt + (size_t)(bh * 64 + d) * 1024 + t0 + c8) = o;
  }
}

// ---------------- LayerNorm (row = 1024 fp32) -> bf16 ----------------
__global__ __launch_bounds__(256) void ln_bf16(const float* __restrict__ x,
                                               const float* __restrict__ gg,
                                               const float* __restrict__ bb,
                                               u16* __restrict__ out) {
  const int row = blockIdx.x;
  const float4 v = ((const float4*)(x + (size_t)row * 1024))[threadIdx.x];
  float s  = v.x + v.y + v.z + v.w;
  float s2 = v.x * v.x + v.y * v.y + v.z * v.z + v.w * v.w;
#pragma unroll
  for (int m = 1; m < 64; m <<= 1) { s += __shfl_xor(s, m); s2 += __shfl_xor(s2, m); }
  __shared__ float ps[4], ps2[4];
  const int wave = threadIdx.x >> 6;
  if ((threadIdx.x & 63) == 0) { ps[wave] = s; ps2[wave] = s2; }
  __syncthreads();
  s = ps[0] + ps[1] + ps[2] + ps[3];
  s2 = ps2[0] + ps2[1] + ps2[2] + ps2[3];
  const float mu = s * (1.0f / 1024.0f);
  const float var = s2 * (1.0f / 1024.0f) - mu * mu;
  const float rs = rsqrtf(var + 1e-6f);
  const float4 gv = ((const float4*)gg)[threadIdx.x];
  const float4 bv = ((const float4*)bb)[threadIdx.x];
  ushort4 o;
  o.x = f2bf((v.x - mu) * rs * gv.x + bv.x);
  o.y = f2bf((v.y - mu) * rs * gv.y + bv.y);
  o.z = f2bf((v.z - mu) * rs * gv.z + bv.z);
  o.w = f2bf((v.w - mu) * rs * gv.w + bv.w);
  ((ushort4*)(out + (size_t)row * 1024))[threadIdx.x] = o;
}

// ---------------- GEMM 256x128, BK=64, 8 waves, single-buffer LDS ---------
template <bool GELU_, bool OUTBF>
__global__ __launch_bounds__(512, 4) void gemmS(
    const u16* __restrict__ A, const u16* __restrict__ W,
    const float* __restrict__ bias, void* __restrict__ out,
    int M, int N, int K) {
  __shared__ __align__(16) u16 As[256 * 64];   // 32 KB
  __shared__ __align__(16) u16 Bs[128 * 64];   // 16 KB
  const int tid = threadIdx.x;
  const int wave = tid >> 6, lane = tid & 63;
  const int g = lane >> 4, lr = lane & 15;
  const int wm = wave >> 1, wn = wave & 1;
  const int ntile = N >> 7;
  const int nwg = gridDim.x;
  int bid = blockIdx.x;
  bid = (bid & 7) * (nwg >> 3) + (bid >> 3);   // XCD swizzle (grid % 8 == 0)
  const int brow = (bid / ntile) << 8, bcol = (bid % ntile) << 7;

  const int sru = wave * 8 + (lane >> 3);
  const int scg = (lane & 7) ^ (lane >> 3);
  const int swz = (lr & 7) << 4;

  f32x4 acc[4][4];
#pragma unroll
  for (int i = 0; i < 4; ++i)
#pragma unroll
    for (int j = 0; j < 4; ++j) acc[i][j] = (f32x4){0.f, 0.f, 0.f, 0.f};

  for (int k0 = 0; k0 < K; k0 += 64) {
#pragma unroll
    for (int u = 0; u < 2; ++u)
      async_ld16(W + (size_t)(bcol + u * 64 + sru) * K + k0 + scg * 8,
                 (char*)Bs + u * 8192 + wave * 1024);
#pragma unroll
    for (int u = 0; u < 4; ++u)
      async_ld16(A + (size_t)(brow + u * 64 + sru) * K + k0 + scg * 8,
                 (char*)As + u * 8192 + wave * 1024);
    asm volatile("s_waitcnt vmcnt(0)" ::: "memory");
    __builtin_amdgcn_s_barrier();

    short8 bf[4][2];
#pragma unroll
    for (int nf = 0; nf < 4; ++nf) {
      const int row = wn * 64 + nf * 16 + lr;
#pragma unroll
      for (int kk = 0; kk < 2; ++kk)
        bf[nf][kk] = *(const short8*)((const char*)Bs + row * 128 +
                                      ((kk * 64 + g * 16) ^ swz));
    }
    __builtin_amdgcn_s_setprio(1);
#pragma unroll
    for (int mf = 0; mf < 4; ++mf) {
      short8 af[2];
      const int row = wm * 64 + mf * 16 + lr;
#pragma unroll
      for (int kk = 0; kk < 2; ++kk)
        af[kk] = *(const short8*)((const char*)As + row * 128 +
                                  ((kk * 64 + g * 16) ^ swz));
#pragma unroll
      for (int nf = 0; nf < 4; ++nf)
#pragma unroll
        for (int kk = 0; kk < 2; ++kk)
          acc[mf][nf] = __builtin_amdgcn_mfma_f32_16x16x32_bf16(
              af[kk], bf[nf][kk], acc[mf][nf], 0, 0, 0);
    }
    __builtin_amdgcn_s_setprio(0);
    __builtin_amdgcn_s_barrier();
  }

#pragma unroll
  for (int mf = 0; mf < 4; ++mf)
#pragma unroll
    for (int nf = 0; nf < 4; ++nf) {
      const int cI = bcol + wn * 64 + nf * 16 + lr;
      const float bv = bias[cI];
#pragma unroll
      for (int reg = 0; reg < 4; ++reg) {
        const int r = brow + wm * 64 + mf * 16 + g * 4 + reg;
        float v = acc[mf][nf][reg] + bv;
        if (GELU_) v = 0.5f * v * (1.0f + erff(v * 0.70710678118654752f));
        if (OUTBF) ((u16*)out)[(size_t)r * N + cI] = f2bf(v);
        else       ((float*)out)[(size_t)r * N + cI] = v;
      }
    }
}

// ---------------- GEMM 256x128, 4 WIDE waves (128x64 each): low LDS-BW ----
// r20 diagnosis: all 64x64-wave variants are LDS-read-BW bound
// (512 B/MFMA at 85 B/cy >> MFMA pipe).  128x64 wave tile cuts fragment
// traffic to 384 B/MFMA (24 ds_read_b128 per 64 MFMA).  256 threads,
// single-buffer 48 KB, 12 staging loads/thread, same swizzle invariant.
template <bool GELU_, bool OUTBF>
__global__ __launch_bounds__(256) void gemmW(
    const u16* __restrict__ A, const u16* __restrict__ W,
    const float* __restrict__ bias, void* __restrict__ out,
    int M, int N, int K) {
  __shared__ __align__(16) u16 As[256 * 64];   // 32 KB
  __shared__ __align__(16) u16 Bs[128 * 64];   // 16 KB
  const int tid = threadIdx.x;
  const int wave = tid >> 6, lane = tid & 63;
  const int g = lane >> 4, lr = lane & 15;
  const int wm = wave >> 1, wn = wave & 1;     // 2x2 waves, each 128x64 out
  const int ntile = N >> 7;
  const int nwg = gridDim.x;
  int bid = blockIdx.x;
  bid = (bid & 7) * (nwg >> 3) + (bid >> 3);   // XCD swizzle (grid % 8 == 0)
  const int brow = (bid / ntile) << 8, bcol = (bid % ntile) << 7;

  const int sr0 = tid >> 3;                    // stage row 0..31 (+u*32)
  const int scg = (tid & 7) ^ (sr0 & 7);       // pre-swizzled granule
  const int swz = (lr & 7) << 4;

  f32x4 acc[8][4];
#pragma unroll
  for (int i = 0; i < 8; ++i)
#pragma unroll
    for (int j = 0; j < 4; ++j) acc[i][j] = (f32x4){0.f, 0.f, 0.f, 0.f};

  for (int k0 = 0; k0 < K; k0 += 64) {
#pragma unroll
    for (int u = 0; u < 4; ++u)
      async_ld16(W + (size_t)(bcol + u * 32 + sr0) * K + k0 + scg * 8,
                 (char*)Bs + u * 4096 + tid * 16);
#pragma unroll
    for (int u = 0; u < 8; ++u)
      async_ld16(A + (size_t)(brow + u * 32 + sr0) * K + k0 + scg * 8,
                 (char*)As + u * 4096 + tid * 16);
    asm volatile("s_waitcnt vmcnt(0)" ::: "memory");
    __builtin_amdgcn_s_barrier();

    short8 bf[4][2];
#pragma unroll
    for (int nf = 0; nf < 4; ++nf) {
      const int row = wn * 64 + nf * 16 + lr;
#pragma unroll
      for (int kk = 0; kk < 2; ++kk)
        bf[nf][kk] = *(const short8*)((const char*)Bs + row * 128 +
                                      ((kk * 64 + g * 16) ^ swz));
    }
    __builtin_amdgcn_s_setprio(1);
#pragma unroll
    for (int mf = 0; mf < 8; ++mf) {
      short8 af[2];
      const int row = wm * 128 + mf * 16 + lr;
#pragma unroll
      for (int kk = 0; kk < 2; ++kk)
        af[kk] = *(const short8*)((const char*)As + row * 128 +
                                  ((kk * 64 + g * 16) ^ swz));
#pragma unroll
      for (int nf = 0; nf < 4; ++nf)
#pragma unroll
        for (int kk = 0; kk < 2; ++kk)
          acc[mf][nf] = __builtin_amdgcn_mfma_f32_16x16x32_bf16(
              af[kk], bf[nf][kk], acc[mf][nf], 0, 0, 0);
    }
    __builtin_amdgcn_s_setprio(0);
    __builtin_amdgcn_s_barrier();
  }

#pragma unroll
  for (int mf = 0; mf < 8; ++mf)
#pragma unroll
    for (int nf = 0; nf < 4; ++nf) {
      const int cI = bcol + wn * 64 + nf * 16 + lr;
      const float bv = bias[cI];
#pragma unroll
      for (int reg = 0; reg < 4; ++reg) {
        const int r = brow + wm * 128 + mf * 16 + g * 4 + reg;
        float v = acc[mf][nf][reg] + bv;
        if (GELU_) v = 0.5f * v * (1.0f + erff(v * 0.70710678118654752f));
        if (OUTBF) ((u16*)out)[(size_t)r * N + cI] = f2bf(v);
        else       ((float*)out)[(size_t)r * N + cI] = v;
      }
    }
}

// ---------------- GEMM 256x96 (for qkv: grid 16x32 = 512 = even 2/CU) -----
template <bool GELU_, bool OUTBF>
__global__ __launch_bounds__(512, 4) void gemmS96(
    const u16* __restrict__ A, const u16* __restrict__ W,
    const float* __restrict__ bias, void* __restrict__ out,
    int M, int N, int K) {
  __shared__ __align__(16) u16 As[256 * 64];   // 32 KB
  __shared__ __align__(16) u16 Bs[96 * 64];    // 12 KB
  const int tid = threadIdx.x;
  const int wave = tid >> 6, lane = tid & 63;
  const int g = lane >> 4, lr = lane & 15;
  const int wm = wave >> 1, wn = wave & 1;     // 4m x 2n -> wave: 64 x 48
  const int ntile = N / 96;
  const int nwg = gridDim.x;
  int bid = blockIdx.x;
  bid = (bid & 7) * (nwg >> 3) + (bid >> 3);   // XCD swizzle (grid % 8 == 0)
  const int brow = (bid / ntile) << 8;
  const int bcol = (bid % ntile) * 96;

  const int sru = wave * 8 + (lane >> 3);
  const int scg = (lane & 7) ^ (lane >> 3);
  const int swz = (lr & 7) << 4;
  const int brG = tid >> 3;                    // B stage row 0..63
  const int bcg = (tid & 7) ^ (brG & 7);       // pre-swizzled granule

  f32x4 acc[4][3];
#pragma unroll
  for (int i = 0; i < 4; ++i)
#pragma unroll
    for (int j = 0; j < 3; ++j) acc[i][j] = (f32x4){0.f, 0.f, 0.f, 0.f};

  for (int k0 = 0; k0 < K; k0 += 64) {
    async_ld16(W + (size_t)(bcol + brG) * K + k0 + bcg * 8,
               (char*)Bs + tid * 16);
    if (wave < 4)
      async_ld16(W + (size_t)(bcol + 64 + brG) * K + k0 + bcg * 8,
                 (char*)Bs + 8192 + tid * 16);
#pragma unroll
    for (int u = 0; u < 4; ++u)
      async_ld16(A + (size_t)(brow + u * 64 + sru) * K + k0 + scg * 8,
                 (char*)As + u * 8192 + wave * 1024);
    asm volatile("s_waitcnt vmcnt(0)" ::: "memory");
    __builtin_amdgcn_s_barrier();

    short8 bf[3][2];
#pragma unroll
    for (int nf = 0; nf < 3; ++nf) {
      const int row = wn * 48 + nf * 16 + lr;
#pragma unroll
      for (int kk = 0; kk < 2; ++kk)
        bf[nf][kk] = *(const short8*)((const char*)Bs + row * 128 +
                                      ((kk * 64 + g * 16) ^ swz));
    }
    __builtin_amdgcn_s_setprio(1);
#pragma unroll
    for (int mf = 0; mf < 4; ++mf) {
      short8 af[2];
      const int row = wm * 64 + mf * 16 + lr;
#pragma unroll
      for (int kk = 0; kk < 2; ++kk)
        af[kk] = *(const short8*)((const char*)As + row * 128 +
                                  ((kk * 64 + g * 16) ^ swz));
#pragma unroll
      for (int nf = 0; nf < 3; ++nf)
#pragma unroll
        for (int kk = 0; kk < 2; ++kk)
          acc[mf][nf] = __builtin_amdgcn_mfma_f32_16x16x32_bf16(
              af[kk], bf[nf][kk], acc[mf][nf], 0, 0, 0);
    }
    __builtin_amdgcn_s_setprio(0);
    __builtin_amdgcn_s_barrier();
  }

#pragma unroll
  for (int mf = 0; mf < 4; ++mf)
#pragma unroll
    for (int nf = 0; nf < 3; ++nf) {
      const int cI = bcol + wn * 48 + nf * 16 + lr;
      const float bv = bias[cI];
#pragma unroll
      for (int reg = 0; reg < 4; ++reg) {
        const int r = brow + wm * 64 + mf * 16 + g * 4 + reg;
        float v = acc[mf][nf][reg] + bv;
        if (GELU_) v = 0.5f * v * (1.0f + erff(v * 0.70710678118654752f));
        if (OUTBF) ((u16*)out)[(size_t)r * N + cI] = f2bf(v);
        else       ((float*)out)[(size_t)r * N + cI] = v;
      }
    }
}

// ---------------- GEMM 128x128 TRIPLE-buffer (grid 256 ONLY: L2-resident) -
template <bool GELU_, bool RESID, bool OUTBF>
__global__ __launch_bounds__(512, 2) void gemm128t(
    const u16* __restrict__ A, const u16* __restrict__ W,
    const float* __restrict__ bias, const float* __restrict__ resid,
    void* __restrict__ out, int M, int N, int K) {
  __shared__ __align__(16) u16 smem[49152];   // 96 KB: 3 x (A 16K | B 16K)
  const int tid = threadIdx.x;
  const int wave = tid >> 6, lane = tid & 63;
  const int g = lane >> 4, lr = lane & 15;
  const int kg = wave & 1, ws = wave >> 1;
  const int wm = ws >> 1, wn = ws & 1;
  const int ntile = N >> 7;
  const int nwg = gridDim.x;
  int bid = blockIdx.x;
  bid = (bid & 7) * (nwg >> 3) + (bid >> 3);   // grid % 8 == 0
  const int brow = (bid / ntile) << 7, bcol = (bid % ntile) << 7;

  const int sru = wave * 8 + (lane >> 3);
  const int scg = (lane & 7) ^ (lane >> 3);
  const int NT = K >> 6;

  f32x4 acc[4][4];
#pragma unroll
  for (int i = 0; i < 4; ++i)
#pragma unroll
    for (int j = 0; j < 4; ++j) acc[i][j] = (f32x4){0.f, 0.f, 0.f, 0.f};

  auto STAGE = [&](int b, int kt) {
    char* base = (char*)smem + b * 32768;
#pragma unroll
    for (int u = 0; u < 2; ++u)
      async_ld16(W + (size_t)(bcol + u * 64 + sru) * K + (size_t)kt * 64 + scg * 8,
                 base + 16384 + u * 8192 + wave * 1024);
#pragma unroll
    for (int u = 0; u < 2; ++u)
      async_ld16(A + (size_t)(brow + u * 64 + sru) * K + (size_t)kt * 64 + scg * 8,
                 base + u * 8192 + wave * 1024);
  };

  const int colb = kg * 64 + g * 16;
  const int swz = (lr & 7) << 4;

  STAGE(0, 0);
  STAGE(1, 1 < NT ? 1 : 0);
  asm volatile("s_waitcnt vmcnt(4)" ::: "memory");
  __builtin_amdgcn_s_barrier();

  for (int t = 0; t < NT; ++t) {
    const int b = t % 3;
    const char* Ab = (const char*)smem + b * 32768;
    const char* Bb = Ab + 16384;

    short8 bf[4], af[4];
#pragma unroll
    for (int nf = 0; nf < 4; ++nf)
      bf[nf] = *(const short8*)(Bb + (wn * 64 + nf * 16 + lr) * 128 +
                                (colb ^ swz));
#pragma unroll
    for (int mf = 0; mf < 2; ++mf) {
      af[mf]     = *(const short8*)(Ab + (wm * 32 + mf * 16 + lr) * 128 +
                                    (colb ^ swz));
      af[mf + 2] = *(const short8*)(Ab + (64 + wm * 32 + mf * 16 + lr) * 128 +
                                    (colb ^ swz));
    }
    {
      const int pt = (t + 2 < NT) ? t + 2 : NT - 1;
      STAGE((t + 2) % 3, pt);
    }
    __builtin_amdgcn_s_setprio(1);
#pragma unroll
    for (int mf = 0; mf < 4; ++mf)
#pragma unroll
      for (int nf = 0; nf < 4; ++nf)
        acc[mf][nf] = __builtin_amdgcn_mfma_f32_16x16x32_bf16(
            af[mf], bf[nf], acc[mf][nf], 0, 0, 0);
    __builtin_amdgcn_s_setprio(0);
    asm volatile("s_waitcnt vmcnt(4)" ::: "memory");
    __builtin_amdgcn_s_barrier();
  }

  asm volatile("s_waitcnt vmcnt(0)" ::: "memory");
  __syncthreads();
  float* pr = (float*)smem + (size_t)((wm << 1) | wn) * 4096;
  if (kg == 1) {
#pragma unroll
    for (int mf = 0; mf < 4; ++mf)
#pragma unroll
      for (int nf = 0; nf < 4; ++nf)
#pragma unroll
        for (int reg = 0; reg < 4; ++reg) {
          const int lrow = mf * 16 + g * 4 + reg;
          const int w = lrow * 64 +
                        ((nf * 16 + lr) ^ (g << 2) ^ ((g & 1) << 4));
          pr[w] = acc[mf][nf][reg];
        }
  }
  __syncthreads();
  if (kg == 0) {
#pragma unroll
    for (int mf = 0; mf < 4; ++mf) {
      const int rb = brow + ((mf < 2) ? wm * 32 + mf * 16
                                      : 64 + wm * 32 + (mf - 2) * 16);
#pragma unroll
      for (int nf = 0; nf < 4; ++nf) {
        const int cI = bcol + wn * 64 + nf * 16 + lr;
        const float bv = bias[cI];
#pragma unroll
        for (int reg = 0; reg < 4; ++reg) {
          const int lrow = mf * 16 + g * 4 + reg;
          const int w = lrow * 64 +
                        ((nf * 16 + lr) ^ (g << 2) ^ ((g & 1) << 4));
          const int r = rb + g * 4 + reg;
          float v = acc[mf][nf][reg] + pr[w] + bv;
          if (GELU_) v = 0.5f * v * (1.0f + erff(v * 0.70710678118654752f));
          if (RESID) v += resid[(size_t)r * N + cI];
          if (OUTBF) ((u16*)out)[(size_t)r * N + cI] = f2bf(v);
          else       ((float*)out)[(size_t)r * N + cI] = v;
        }
      }
    }
  }
}

// ---------------- Flash attention: 8 waves, 128 q-rows/block (r18 best) ---
__global__ __launch_bounds__(512) void attn_kernel(const u16* __restrict__ qkv,
                                                   const u16* __restrict__ vt,
                                                   u16* __restrict__ o_out) {
  const int D = blockIdx.x;
  const int bh = (D & 7) + 8 * (D >> 6);   // same (b,h) -> same XCD
  const int qb = (D >> 3) & 7;
  const int b = bh >> 4, h = bh & 15;
  const int tid = threadIdx.x, wave = tid >> 6, lane = tid & 63;
  const int g = lane >> 4, lr = lane & 15;
  const u16* qg = qkv + (size_t)b * Nn * 3072 + h * 64;
  const u16* kg = qg + 1024;
  const u16* vgt = vt + (size_t)bh * 64 * 1024;

  __shared__ __align__(16) u16 Kl[64 * 64];
  __shared__ __align__(16) u16 Vt[64 * 64];
  __shared__ __align__(16) u16 Pl[128 * 64];

  const int q0 = qb * 128 + wave * 16;
  short8 qf[2];
#pragma unroll
  for (int kf = 0; kf < 2; ++kf)
    qf[kf] = *(const short8*)(qg + (size_t)(q0 + lr) * 3072 + kf * 32 + g * 8);

  f32x4 o[4];
  float ll[4];
#pragma unroll
  for (int df = 0; df < 4; ++df) o[df] = (f32x4){0.f, 0.f, 0.f, 0.f};
#pragma unroll
  for (int r = 0; r < 4; ++r) ll[r] = 0.f;

  const int sc = wave * 64 + lane;             // granule id 0..511
  const int st = sc >> 3;                      // tile row 0..63
  const int sob = ((sc & 7) << 4) ^ ((st & 7) << 4);

  for (int t0 = 0; t0 < Nn; t0 += 64) {
    async_ld16(kg + (size_t)(t0 + st) * 3072 + (sob >> 1),
               (char*)Kl + (size_t)(wave * 64) * 16);
    async_ld16(vgt + (size_t)st * 1024 + t0 + (sob >> 1),
               (char*)Vt + (size_t)(wave * 64) * 16);
    __syncthreads();

    short8 kfr[4][2];
#pragma unroll
    for (int tf = 0; tf < 4; ++tf) {
      const int t = tf * 16 + lr;
#pragma unroll
      for (int kf = 0; kf < 2; ++kf)
        kfr[tf][kf] = *(const short8*)((const char*)Kl + t * 128 +
                                       ((kf * 64 + g * 16) ^ ((t & 7) << 4)));
    }
    f32x4 s[4];
    __builtin_amdgcn_s_setprio(1);
#pragma unroll
    for (int tf = 0; tf < 4; ++tf) {
      f32x4 z = (f32x4){0.f, 0.f, 0.f, 0.f};
      z = __builtin_amdgcn_mfma_f32_16x16x32_bf16(qf[0], kfr[tf][0], z, 0, 0, 0);
      z = __builtin_amdgcn_mfma_f32_16x16x32_bf16(qf[1], kfr[tf][1], z, 0, 0, 0);
      s[tf] = z;
    }
    __builtin_amdgcn_s_setprio(0);

    short8 vfr[4][2];
#pragma unroll
    for (int df = 0; df < 4; ++df) {
      const int d = df * 16 + lr;
#pragma unroll
      for (int kf = 0; kf < 2; ++kf)
        vfr[df][kf] = *(const short8*)((const char*)Vt + d * 128 +
                                       ((kf * 64 + g * 16) ^ ((d & 7) << 4)));
    }

    // no-max softmax (exp safe in fp32 for LN'd inputs); deferred row-reduce
#pragma unroll
    for (int tf = 0; tf < 4; ++tf)
#pragma unroll
      for (int reg = 0; reg < 4; ++reg) {
        const float p = __expf(s[tf][reg] * 0.125f);
        s[tf][reg] = p;
        ll[reg] += p;
      }

#pragma unroll
    for (int tf = 0; tf < 4; ++tf)
#pragma unroll
      for (int reg = 0; reg < 4; ++reg) {
        const int m = wave * 16 + g * 4 + reg;
        const int t2 = (tf * 16 + lr) * 2;
        *(u16*)((char*)Pl + m * 128 + (t2 ^ ((m & 7) << 4))) = f2bf(s[tf][reg]);
      }
    short8 pa[2];
#pragma unroll
    for (int kf = 0; kf < 2; ++kf)
      pa[kf] = *(const short8*)((const char*)Pl + (wave * 16 + lr) * 128 +
                                ((kf * 64 + g * 16) ^ ((lr & 7) << 4)));
    __builtin_amdgcn_s_setprio(1);
#pragma unroll
    for (int df = 0; df < 4; ++df) {
      o[df] = __builtin_amdgcn_mfma_f32_16x16x32_bf16(pa[0], vfr[df][0], o[df], 0, 0, 0);
      o[df] = __builtin_amdgcn_mfma_f32_16x16x32_bf16(pa[1], vfr[df][1], o[df], 0, 0, 0);
    }
    __builtin_amdgcn_s_setprio(0);
    __syncthreads();
  }

#pragma unroll
  for (int reg = 0; reg < 4; ++reg) {
#pragma unroll
    for (int msk = 1; msk < 16; msk <<= 1) ll[reg] += __shfl_xor(ll[reg], msk);
    const float inv = 1.0f / ll[reg];
    const int row = b * Nn + qb * 128 + wave * 16 + g * 4 + reg;
#pragma unroll
    for (int df = 0; df < 4; ++df) {
      const int col = h * 64 + df * 16 + lr;
      o_out[(size_t)row * 1024 + col] = f2bf(o[df][reg] * inv);
    }
  }
}

// ---------------- launch ----------------
extern "C" void kernel_launch(void* const* d_in, const int* in_sizes, int n_in,
                              void* d_out, int out_size, void* d_ws, size_t ws_size,
                              hipStream_t stream) {
  const float* x    = (const float*)d_in[0];
  const float* qkvw = (const float*)d_in[1];
  const float* qkvb = (const float*)d_in[2];
  const float* apw  = (const float*)d_in[3];
  const float* apb  = (const float*)d_in[4];
  const float* bpw  = (const float*)d_in[5];
  const float* bpb  = (const float*)d_in[6];
  const float* ln1g = (const float*)d_in[7];
  const float* ln1b = (const float*)d_in[8];
  const float* ln2g = (const float*)d_in[9];
  const float* ln2b = (const float*)d_in[10];
  const float* fc1w = (const float*)d_in[11];
  const float* fc1b = (const float*)d_in[12];
  const float* fc2w = (const float*)d_in[13];
  const float* fc2b = (const float*)d_in[14];
  float* out = (float*)d_out;

  char* ws = (char*)d_ws;
  size_t off = 0;
  auto alloc = [&](size_t bytes) {
    char* p = ws + off;
    off += (bytes + 255) & ~(size_t)255;
    return p;
  };
  u16* wqkv  = (u16*)alloc((size_t)3145728 * 2);
  u16* wap   = (u16*)alloc((size_t)1048576 * 2);   // hole, never written/read
  u16* wbp   = (u16*)alloc((size_t)1048576 * 2);
  u16* wfc1  = (u16*)alloc((size_t)4194304 * 2);
  u16* wfc2  = (u16*)alloc((size_t)4194304 * 2);
  u16* xn    = (u16*)alloc((size_t)4194304 * 2);
  u16* qkvbf = (u16*)alloc((size_t)12582912 * 2);
  u16* obuf  = (u16*)alloc((size_t)4194304 * 2);
  float* x2  = (float*)alloc((size_t)4194304 * 4);
  u16* wapT  = (u16*)alloc((size_t)1048576 * 2);   // Wap^T bf16
  u16* wc    = (u16*)alloc((size_t)1048576 * 2);   // Wc = Wbp@Wap bf16
  float* cb  = (float*)alloc(1024 * 4);            // combined bias
  u16* vt    = (u16*)alloc((size_t)4194304 * 2);   // V^T per (b,h): [64][1024]
  u16* ff    = qkvbf;
  (void)wap;

  cvt_all<<<12288, 256, 0, stream>>>(qkvw, bpw, fc1w, fc2w, wqkv);
  transpose_wT<<<256, 256, 0, stream>>>(apw, wapT);
  cbias_k<<<256, 256, 0, stream>>>(apb, bpw, bpb, cb);

  // Wc = Wbp @ Wap  (wc[i,j] = sum_k wbp[i,k] * wapT[j,k])
  gemm64<<<256, 256, 0, stream>>>(wbp, wapT, wc, 1024);

  ln_bf16<<<4096, 256, 0, stream>>>(x, ln1g, ln1b, xn);

  // qkv = xn @ qkv_w^T + b : [4096,3072] -- 256x96 tiles, grid 512 (even)
  gemmS96<false, true><<<512, 512, 0, stream>>>(
      xn, wqkv, qkvb, qkvbf, 4096, 3072, 1024);

  vtrans<<<1024, 256, 0, stream>>>(qkvbf, vt);

  attn_kernel<<<512, 512, 0, stream>>>(qkvbf, vt, obuf);

  // x2 = x + obuf @ Wc^T + cb   (fused attn_proj + blk_proj + residual)
  gemm128t<false, true, false><<<256, 512, 0, stream>>>(
      obuf, wc, cb, x, x2, 4096, 1024, 1024);

  ln_bf16<<<4096, 256, 0, stream>>>(x2, ln2g, ln2b, xn);

  // ff = gelu(h @ fc1_w^T + b) : [4096,4096] -- WIDE waves (128x64), grid 512
  gemmW<true, true><<<512, 256, 0, stream>>>(
      xn, wfc1, fc1b, ff, 4096, 4096, 1024);

  // out = x2 + ff @ fc2_w^T + b  (fp32)
  gemm128t<false, true, false><<<256, 512, 0, stream>>>(
      ff, wfc2, fc2b, x2, out, 4096, 1024, 4096);
}

// Round 22
// 218.460 us; speedup vs baseline: 1.2394x; 1.2394x over previous
//
#include <hip/hip_runtime.h>

typedef unsigned short u16;
typedef __attribute__((ext_vector_type(8))) short short8;
typedef __attribute__((ext_vector_type(4))) float f32x4;

#define DEVI __device__ __forceinline__

static constexpr int Nn = 1024;   // sequence length
static constexpr int Cc = 1024;   // channels

DEVI u16 f2bf(float f) {
  union { float f; unsigned u; } v; v.f = f;
  unsigned r = v.u + 0x7fffu + ((v.u >> 16) & 1u);
  return (u16)(r >> 16);
}

DEVI void async_ld16(const void* g, void* lds) {
  __builtin_amdgcn_global_load_lds(
      (__attribute__((address_space(1))) void*)g,
      (__attribute__((address_space(3))) void*)lds, 16, 0, 0);
}

// ---------------- fused fp32 -> bf16 weight convert (skips unused apw) ----
__global__ __launch_bounds__(256) void cvt_all(
    const float* __restrict__ s0, const float* __restrict__ s2,
    const float* __restrict__ s3, const float* __restrict__ s4,
    u16* __restrict__ out) {
  const size_t j = ((size_t)blockIdx.x * 256 + threadIdx.x) * 4;
  size_t i; const float* src; size_t lo;
  if (j < 3145728) { i = j; src = s0; lo = 0; }
  else {
    i = j + 1048576;
    if (i < 5242880)      { src = s2; lo = 4194304; }
    else if (i < 9437184) { src = s3; lo = 5242880; }
    else                  { src = s4; lo = 9437184; }
  }
  const float4 v = *(const float4*)&src[i - lo];
  ushort4 o;
  o.x = f2bf(v.x); o.y = f2bf(v.y); o.z = f2bf(v.z); o.w = f2bf(v.w);
  *(ushort4*)&out[i] = o;
}

// ---------------- transpose 1024x1024 fp32 -> bf16 (out[j,i] = in[i,j]) ----
__global__ __launch_bounds__(256) void transpose_wT(const float* __restrict__ in,
                                                    u16* __restrict__ out) {
  __shared__ u16 tile[64][72];
  const int bx = blockIdx.x & 15, by = blockIdx.x >> 4;
  const int tr = threadIdx.x >> 2;
  const int tc4 = (threadIdx.x & 3) * 16;
#pragma unroll
  for (int j = 0; j < 4; ++j) {
    const float4 v = *(const float4*)&in[(size_t)(by * 64 + tr) * 1024 +
                                         bx * 64 + tc4 + j * 4];
    tile[tc4 + j * 4 + 0][tr] = f2bf(v.x);
    tile[tc4 + j * 4 + 1][tr] = f2bf(v.y);
    tile[tc4 + j * 4 + 2][tr] = f2bf(v.z);
    tile[tc4 + j * 4 + 3][tr] = f2bf(v.w);
  }
  __syncthreads();
#pragma unroll
  for (int j = 0; j < 4; ++j) {
    ushort4 o;
    o.x = tile[tr][tc4 + j * 4 + 0];
    o.y = tile[tr][tc4 + j * 4 + 1];
    o.z = tile[tr][tc4 + j * 4 + 2];
    o.w = tile[tr][tc4 + j * 4 + 3];
    *(ushort4*)&out[(size_t)(bx * 64 + tr) * 1024 + by * 64 + tc4 + j * 4] = o;
  }
}

// ---------------- combined bias: cb[j] = bpb[j] + dot(apb, bpw_row_j) ------
__global__ __launch_bounds__(256) void cbias_k(const float* __restrict__ apb,
                                               const float* __restrict__ bpw,
                                               const float* __restrict__ bpb,
                                               float* __restrict__ cb) {
  const int j = blockIdx.x * 4 + (threadIdx.x >> 6);
  const int lane = threadIdx.x & 63;
  float s = 0.f;
  for (int k = lane; k < 1024; k += 64) s += apb[k] * bpw[(size_t)j * 1024 + k];
#pragma unroll
  for (int m = 1; m < 64; m <<= 1) s += __shfl_xor(s, m);
  if (lane == 0) cb[j] = s + bpb[j];
}

// ---------------- GEMM 64x64 tile (for the 1024^3 Wc precompute) ----------
__global__ __launch_bounds__(256) void gemm64(const u16* __restrict__ A,
                                              const u16* __restrict__ W,
                                              u16* __restrict__ out, int K) {
  __shared__ __align__(16) u16 As[64 * 64];
  __shared__ __align__(16) u16 Bs[64 * 64];
  const int tid = threadIdx.x;
  const int wave = tid >> 6, lane = tid & 63;
  const int g = lane >> 4, lr = lane & 15;
  const int brow = (blockIdx.x >> 4) << 6, bcol = (blockIdx.x & 15) << 6;
  const int srow = lane >> 3;
  const int scg = (lane & 7) ^ srow;
  const int swz = (lr & 7) << 4;

  f32x4 acc[4];
#pragma unroll
  for (int j = 0; j < 4; ++j) acc[j] = (f32x4){0.f, 0.f, 0.f, 0.f};

  for (int k0 = 0; k0 < K; k0 += 64) {
#pragma unroll
    for (int u = 0; u < 2; ++u) {
      async_ld16(A + (size_t)(brow + u * 32 + wave * 8 + srow) * K + k0 + scg * 8,
                 (char*)As + u * 4096 + wave * 1024);
      async_ld16(W + (size_t)(bcol + u * 32 + wave * 8 + srow) * K + k0 + scg * 8,
                 (char*)Bs + u * 4096 + wave * 1024);
    }
    __syncthreads();
    short8 af[2], bf[4][2];
#pragma unroll
    for (int kk = 0; kk < 2; ++kk)
      af[kk] = *(const short8*)((char*)As + (wave * 16 + lr) * 128 +
                                ((kk * 64 + g * 16) ^ swz));
#pragma unroll
    for (int nf = 0; nf < 4; ++nf)
#pragma unroll
      for (int kk = 0; kk < 2; ++kk)
        bf[nf][kk] = *(const short8*)((char*)Bs + (nf * 16 + lr) * 128 +
                                      ((kk * 64 + g * 16) ^ swz));
#pragma unroll
    for (int kk = 0; kk < 2; ++kk)
#pragma unroll
      for (int nf = 0; nf < 4; ++nf)
        acc[nf] = __builtin_amdgcn_mfma_f32_16x16x32_bf16(af[kk], bf[nf][kk],
                                                          acc[nf], 0, 0, 0);
    __syncthreads();
  }
#pragma unroll
  for (int nf = 0; nf < 4; ++nf)
#pragma unroll
    for (int reg = 0; reg < 4; ++reg)
      out[(size_t)(brow + wave * 16 + g * 4 + reg) * 1024 +
          bcol + nf * 16 + lr] = f2bf(acc[nf][reg]);
}

// ---------------- V transpose: qkv V-part -> vt[b,h][d][t] bf16 -----------
__global__ __launch_bounds__(256) void vtrans(const u16* __restrict__ qkv,
                                              u16* __restrict__ vt) {
  __shared__ u16 tile[64][72];
  const int bh = blockIdx.x >> 4, tb = blockIdx.x & 15;
  const int b = bh >> 4, h = bh & 15;
  const int t0 = tb * 64;
  const int tid = threadIdx.x;
  const int rr = tid >> 3, c8 = (tid & 7) * 8;
#pragma unroll
  for (int r = 0; r < 2; ++r) {
    const int t = r * 32 + rr;
    const short8 v = *(const short8*)(qkv + (size_t)(b * Nn + t0 + t) * 3072 +
                                      2048 + h * 64 + c8);
#pragma unroll
    for (int j = 0; j < 8; ++j) tile[t][c8 + j] = (u16)v[j];
  }
  __syncthreads();
#pragma unroll
  for (int r = 0; r < 2; ++r) {
    const int d = r * 32 + rr;
    short8 o;
#pragma unroll
    for (int j = 0; j < 8; ++j) o[j] = (short)tile[c8 + j][d];
    *(short8*)(vt + (size_t)(bh * 64 + d) * 1024 + t0 + c8) = o;
  }
}

// ---------------- LayerNorm (row = 1024 fp32) -> bf16 ----------------
__global__ __launch_bounds__(256) void ln_bf16(const float* __restrict__ x,
                                               const float* __restrict__ gg,
                                               const float* __restrict__ bb,
                                               u16* __restrict__ out) {
  const int row = blockIdx.x;
  const float4 v = ((const float4*)(x + (size_t)row * 1024))[threadIdx.x];
  float s  = v.x + v.y + v.z + v.w;
  float s2 = v.x * v.x + v.y * v.y + v.z * v.z + v.w * v.w;
#pragma unroll
  for (int m = 1; m < 64; m <<= 1) { s += __shfl_xor(s, m); s2 += __shfl_xor(s2, m); }
  __shared__ float ps[4], ps2[4];
  const int wave = threadIdx.x >> 6;
  if ((threadIdx.x & 63) == 0) { ps[wave] = s; ps2[wave] = s2; }
  __syncthreads();
  s = ps[0] + ps[1] + ps[2] + ps[3];
  s2 = ps2[0] + ps2[1] + ps2[2] + ps2[3];
  const float mu = s * (1.0f / 1024.0f);
  const float var = s2 * (1.0f / 1024.0f) - mu * mu;
  const float rs = rsqrtf(var + 1e-6f);
  const float4 gv = ((const float4*)gg)[threadIdx.x];
  const float4 bv = ((const float4*)bb)[threadIdx.x];
  ushort4 o;
  o.x = f2bf((v.x - mu) * rs * gv.x + bv.x);
  o.y = f2bf((v.y - mu) * rs * gv.y + bv.y);
  o.z = f2bf((v.z - mu) * rs * gv.z + bv.z);
  o.w = f2bf((v.w - mu) * rs * gv.w + bv.w);
  ((ushort4*)(out + (size_t)row * 1024))[threadIdx.x] = o;
}

// ---------------- GEMM 256x128, BK=64, 8 waves, single-buffer LDS ---------
template <bool GELU_, bool OUTBF>
__global__ __launch_bounds__(512, 4) void gemmS(
    const u16* __restrict__ A, const u16* __restrict__ W,
    const float* __restrict__ bias, void* __restrict__ out,
    int M, int N, int K) {
  __shared__ __align__(16) u16 As[256 * 64];   // 32 KB
  __shared__ __align__(16) u16 Bs[128 * 64];   // 16 KB
  const int tid = threadIdx.x;
  const int wave = tid >> 6, lane = tid & 63;
  const int g = lane >> 4, lr = lane & 15;
  const int wm = wave >> 1, wn = wave & 1;
  const int ntile = N >> 7;
  const int nwg = gridDim.x;
  int bid = blockIdx.x;
  bid = (bid & 7) * (nwg >> 3) + (bid >> 3);   // XCD swizzle (grid % 8 == 0)
  const int brow = (bid / ntile) << 8, bcol = (bid % ntile) << 7;

  const int sru = wave * 8 + (lane >> 3);
  const int scg = (lane & 7) ^ (lane >> 3);
  const int swz = (lr & 7) << 4;

  f32x4 acc[4][4];
#pragma unroll
  for (int i = 0; i < 4; ++i)
#pragma unroll
    for (int j = 0; j < 4; ++j) acc[i][j] = (f32x4){0.f, 0.f, 0.f, 0.f};

  for (int k0 = 0; k0 < K; k0 += 64) {
#pragma unroll
    for (int u = 0; u < 2; ++u)
      async_ld16(W + (size_t)(bcol + u * 64 + sru) * K + k0 + scg * 8,
                 (char*)Bs + u * 8192 + wave * 1024);
#pragma unroll
    for (int u = 0; u < 4; ++u)
      async_ld16(A + (size_t)(brow + u * 64 + sru) * K + k0 + scg * 8,
                 (char*)As + u * 8192 + wave * 1024);
    asm volatile("s_waitcnt vmcnt(0)" ::: "memory");
    __builtin_amdgcn_s_barrier();

    short8 bf[4][2];
#pragma unroll
    for (int nf = 0; nf < 4; ++nf) {
      const int row = wn * 64 + nf * 16 + lr;
#pragma unroll
      for (int kk = 0; kk < 2; ++kk)
        bf[nf][kk] = *(const short8*)((const char*)Bs + row * 128 +
                                      ((kk * 64 + g * 16) ^ swz));
    }
    __builtin_amdgcn_s_setprio(1);
#pragma unroll
    for (int mf = 0; mf < 4; ++mf) {
      short8 af[2];
      const int row = wm * 64 + mf * 16 + lr;
#pragma unroll
      for (int kk = 0; kk < 2; ++kk)
        af[kk] = *(const short8*)((const char*)As + row * 128 +
                                  ((kk * 64 + g * 16) ^ swz));
#pragma unroll
      for (int nf = 0; nf < 4; ++nf)
#pragma unroll
        for (int kk = 0; kk < 2; ++kk)
          acc[mf][nf] = __builtin_amdgcn_mfma_f32_16x16x32_bf16(
              af[kk], bf[nf][kk], acc[mf][nf], 0, 0, 0);
    }
    __builtin_amdgcn_s_setprio(0);
    __builtin_amdgcn_s_barrier();
  }

#pragma unroll
  for (int mf = 0; mf < 4; ++mf)
#pragma unroll
    for (int nf = 0; nf < 4; ++nf) {
      const int cI = bcol + wn * 64 + nf * 16 + lr;
      const float bv = bias[cI];
#pragma unroll
      for (int reg = 0; reg < 4; ++reg) {
        const int r = brow + wm * 64 + mf * 16 + g * 4 + reg;
        float v = acc[mf][nf][reg] + bv;
        if (GELU_) v = 0.5f * v * (1.0f + erff(v * 0.70710678118654752f));
        if (OUTBF) ((u16*)out)[(size_t)r * N + cI] = f2bf(v);
        else       ((float*)out)[(size_t)r * N + cI] = v;
      }
    }
}

// ---------------- GEMM 256x96 (for qkv: grid 16x32 = 512 = even 2/CU) -----
template <bool GELU_, bool OUTBF>
__global__ __launch_bounds__(512, 4) void gemmS96(
    const u16* __restrict__ A, const u16* __restrict__ W,
    const float* __restrict__ bias, void* __restrict__ out,
    int M, int N, int K) {
  __shared__ __align__(16) u16 As[256 * 64];   // 32 KB
  __shared__ __align__(16) u16 Bs[96 * 64];    // 12 KB
  const int tid = threadIdx.x;
  const int wave = tid >> 6, lane = tid & 63;
  const int g = lane >> 4, lr = lane & 15;
  const int wm = wave >> 1, wn = wave & 1;     // 4m x 2n -> wave: 64 x 48
  const int ntile = N / 96;
  const int nwg = gridDim.x;
  int bid = blockIdx.x;
  bid = (bid & 7) * (nwg >> 3) + (bid >> 3);   // XCD swizzle (grid % 8 == 0)
  const int brow = (bid / ntile) << 8;
  const int bcol = (bid % ntile) * 96;

  const int sru = wave * 8 + (lane >> 3);
  const int scg = (lane & 7) ^ (lane >> 3);
  const int swz = (lr & 7) << 4;
  const int brG = tid >> 3;                    // B stage row 0..63
  const int bcg = (tid & 7) ^ (brG & 7);       // pre-swizzled granule

  f32x4 acc[4][3];
#pragma unroll
  for (int i = 0; i < 4; ++i)
#pragma unroll
    for (int j = 0; j < 3; ++j) acc[i][j] = (f32x4){0.f, 0.f, 0.f, 0.f};

  for (int k0 = 0; k0 < K; k0 += 64) {
    async_ld16(W + (size_t)(bcol + brG) * K + k0 + bcg * 8,
               (char*)Bs + tid * 16);
    if (wave < 4)
      async_ld16(W + (size_t)(bcol + 64 + brG) * K + k0 + bcg * 8,
                 (char*)Bs + 8192 + tid * 16);
#pragma unroll
    for (int u = 0; u < 4; ++u)
      async_ld16(A + (size_t)(brow + u * 64 + sru) * K + k0 + scg * 8,
                 (char*)As + u * 8192 + wave * 1024);
    asm volatile("s_waitcnt vmcnt(0)" ::: "memory");
    __builtin_amdgcn_s_barrier();

    short8 bf[3][2];
#pragma unroll
    for (int nf = 0; nf < 3; ++nf) {
      const int row = wn * 48 + nf * 16 + lr;
#pragma unroll
      for (int kk = 0; kk < 2; ++kk)
        bf[nf][kk] = *(const short8*)((const char*)Bs + row * 128 +
                                      ((kk * 64 + g * 16) ^ swz));
    }
    __builtin_amdgcn_s_setprio(1);
#pragma unroll
    for (int mf = 0; mf < 4; ++mf) {
      short8 af[2];
      const int row = wm * 64 + mf * 16 + lr;
#pragma unroll
      for (int kk = 0; kk < 2; ++kk)
        af[kk] = *(const short8*)((const char*)As + row * 128 +
                                  ((kk * 64 + g * 16) ^ swz));
#pragma unroll
      for (int nf = 0; nf < 3; ++nf)
#pragma unroll
        for (int kk = 0; kk < 2; ++kk)
          acc[mf][nf] = __builtin_amdgcn_mfma_f32_16x16x32_bf16(
              af[kk], bf[nf][kk], acc[mf][nf], 0, 0, 0);
    }
    __builtin_amdgcn_s_setprio(0);
    __builtin_amdgcn_s_barrier();
  }

#pragma unroll
  for (int mf = 0; mf < 4; ++mf)
#pragma unroll
    for (int nf = 0; nf < 3; ++nf) {
      const int cI = bcol + wn * 48 + nf * 16 + lr;
      const float bv = bias[cI];
#pragma unroll
      for (int reg = 0; reg < 4; ++reg) {
        const int r = brow + wm * 64 + mf * 16 + g * 4 + reg;
        float v = acc[mf][nf][reg] + bv;
        if (GELU_) v = 0.5f * v * (1.0f + erff(v * 0.70710678118654752f));
        if (OUTBF) ((u16*)out)[(size_t)r * N + cI] = f2bf(v);
        else       ((float*)out)[(size_t)r * N + cI] = v;
      }
    }
}

// ---------------- GEMM 128x128 TRIPLE-buffer (grid 256 ONLY: L2-resident) -
template <bool GELU_, bool RESID, bool OUTBF>
__global__ __launch_bounds__(512, 2) void gemm128t(
    const u16* __restrict__ A, const u16* __restrict__ W,
    const float* __restrict__ bias, const float* __restrict__ resid,
    void* __restrict__ out, int M, int N, int K) {
  __shared__ __align__(16) u16 smem[49152];   // 96 KB: 3 x (A 16K | B 16K)
  const int tid = threadIdx.x;
  const int wave = tid >> 6, lane = tid & 63;
  const int g = lane >> 4, lr = lane & 15;
  const int kg = wave & 1, ws = wave >> 1;
  const int wm = ws >> 1, wn = ws & 1;
  const int ntile = N >> 7;
  const int nwg = gridDim.x;
  int bid = blockIdx.x;
  bid = (bid & 7) * (nwg >> 3) + (bid >> 3);   // grid % 8 == 0
  const int brow = (bid / ntile) << 7, bcol = (bid % ntile) << 7;

  const int sru = wave * 8 + (lane >> 3);
  const int scg = (lane & 7) ^ (lane >> 3);
  const int NT = K >> 6;

  f32x4 acc[4][4];
#pragma unroll
  for (int i = 0; i < 4; ++i)
#pragma unroll
    for (int j = 0; j < 4; ++j) acc[i][j] = (f32x4){0.f, 0.f, 0.f, 0.f};

  auto STAGE = [&](int b, int kt) {
    char* base = (char*)smem + b * 32768;
#pragma unroll
    for (int u = 0; u < 2; ++u)
      async_ld16(W + (size_t)(bcol + u * 64 + sru) * K + (size_t)kt * 64 + scg * 8,
                 base + 16384 + u * 8192 + wave * 1024);
#pragma unroll
    for (int u = 0; u < 2; ++u)
      async_ld16(A + (size_t)(brow + u * 64 + sru) * K + (size_t)kt * 64 + scg * 8,
                 base + u * 8192 + wave * 1024);
  };

  const int colb = kg * 64 + g * 16;
  const int swz = (lr & 7) << 4;

  STAGE(0, 0);
  STAGE(1, 1 < NT ? 1 : 0);
  asm volatile("s_waitcnt vmcnt(4)" ::: "memory");
  __builtin_amdgcn_s_barrier();

  for (int t = 0; t < NT; ++t) {
    const int b = t % 3;
    const char* Ab = (const char*)smem + b * 32768;
    const char* Bb = Ab + 16384;

    short8 bf[4], af[4];
#pragma unroll
    for (int nf = 0; nf < 4; ++nf)
      bf[nf] = *(const short8*)(Bb + (wn * 64 + nf * 16 + lr) * 128 +
                                (colb ^ swz));
#pragma unroll
    for (int mf = 0; mf < 2; ++mf) {
      af[mf]     = *(const short8*)(Ab + (wm * 32 + mf * 16 + lr) * 128 +
                                    (colb ^ swz));
      af[mf + 2] = *(const short8*)(Ab + (64 + wm * 32 + mf * 16 + lr) * 128 +
                                    (colb ^ swz));
    }
    {
      const int pt = (t + 2 < NT) ? t + 2 : NT - 1;
      STAGE((t + 2) % 3, pt);
    }
    __builtin_amdgcn_s_setprio(1);
#pragma unroll
    for (int mf = 0; mf < 4; ++mf)
#pragma unroll
      for (int nf = 0; nf < 4; ++nf)
        acc[mf][nf] = __builtin_amdgcn_mfma_f32_16x16x32_bf16(
            af[mf], bf[nf], acc[mf][nf], 0, 0, 0);
    __builtin_amdgcn_s_setprio(0);
    asm volatile("s_waitcnt vmcnt(4)" ::: "memory");
    __builtin_amdgcn_s_barrier();
  }

  asm volatile("s_waitcnt vmcnt(0)" ::: "memory");
  __syncthreads();
  float* pr = (float*)smem + (size_t)((wm << 1) | wn) * 4096;
  if (kg == 1) {
#pragma unroll
    for (int mf = 0; mf < 4; ++mf)
#pragma unroll
      for (int nf = 0; nf < 4; ++nf)
#pragma unroll
        for (int reg = 0; reg < 4; ++reg) {
          const int lrow = mf * 16 + g * 4 + reg;
          const int w = lrow * 64 +
                        ((nf * 16 + lr) ^ (g << 2) ^ ((g & 1) << 4));
          pr[w] = acc[mf][nf][reg];
        }
  }
  __syncthreads();
  if (kg == 0) {
#pragma unroll
    for (int mf = 0; mf < 4; ++mf) {
      const int rb = brow + ((mf < 2) ? wm * 32 + mf * 16
                                      : 64 + wm * 32 + (mf - 2) * 16);
#pragma unroll
      for (int nf = 0; nf < 4; ++nf) {
        const int cI = bcol + wn * 64 + nf * 16 + lr;
        const float bv = bias[cI];
#pragma unroll
        for (int reg = 0; reg < 4; ++reg) {
          const int lrow = mf * 16 + g * 4 + reg;
          const int w = lrow * 64 +
                        ((nf * 16 + lr) ^ (g << 2) ^ ((g & 1) << 4));
          const int r = rb + g * 4 + reg;
          float v = acc[mf][nf][reg] + pr[w] + bv;
          if (GELU_) v = 0.5f * v * (1.0f + erff(v * 0.70710678118654752f));
          if (RESID) v += resid[(size_t)r * N + cI];
          if (OUTBF) ((u16*)out)[(size_t)r * N + cI] = f2bf(v);
          else       ((float*)out)[(size_t)r * N + cI] = v;
        }
      }
    }
  }
}

// ---------------- Flash attention: 8 waves, 128 q-rows/block (r18 best) ---
__global__ __launch_bounds__(512) void attn_kernel(const u16* __restrict__ qkv,
                                                   const u16* __restrict__ vt,
                                                   u16* __restrict__ o_out) {
  const int D = blockIdx.x;
  const int bh = (D & 7) + 8 * (D >> 6);   // same (b,h) -> same XCD
  const int qb = (D >> 3) & 7;
  const int b = bh >> 4, h = bh & 15;
  const int tid = threadIdx.x, wave = tid >> 6, lane = tid & 63;
  const int g = lane >> 4, lr = lane & 15;
  const u16* qg = qkv + (size_t)b * Nn * 3072 + h * 64;
  const u16* kg = qg + 1024;
  const u16* vgt = vt + (size_t)bh * 64 * 1024;

  __shared__ __align__(16) u16 Kl[64 * 64];
  __shared__ __align__(16) u16 Vt[64 * 64];
  __shared__ __align__(16) u16 Pl[128 * 64];

  const int q0 = qb * 128 + wave * 16;
  short8 qf[2];
#pragma unroll
  for (int kf = 0; kf < 2; ++kf)
    qf[kf] = *(const short8*)(qg + (size_t)(q0 + lr) * 3072 + kf * 32 + g * 8);

  f32x4 o[4];
  float ll[4];
#pragma unroll
  for (int df = 0; df < 4; ++df) o[df] = (f32x4){0.f, 0.f, 0.f, 0.f};
#pragma unroll
  for (int r = 0; r < 4; ++r) ll[r] = 0.f;

  const int sc = wave * 64 + lane;             // granule id 0..511
  const int st = sc >> 3;                      // tile row 0..63
  const int sob = ((sc & 7) << 4) ^ ((st & 7) << 4);

  for (int t0 = 0; t0 < Nn; t0 += 64) {
    async_ld16(kg + (size_t)(t0 + st) * 3072 + (sob >> 1),
               (char*)Kl + (size_t)(wave * 64) * 16);
    async_ld16(vgt + (size_t)st * 1024 + t0 + (sob >> 1),
               (char*)Vt + (size_t)(wave * 64) * 16);
    __syncthreads();

    short8 kfr[4][2];
#pragma unroll
    for (int tf = 0; tf < 4; ++tf) {
      const int t = tf * 16 + lr;
#pragma unroll
      for (int kf = 0; kf < 2; ++kf)
        kfr[tf][kf] = *(const short8*)((const char*)Kl + t * 128 +
                                       ((kf * 64 + g * 16) ^ ((t & 7) << 4)));
    }
    f32x4 s[4];
    __builtin_amdgcn_s_setprio(1);
#pragma unroll
    for (int tf = 0; tf < 4; ++tf) {
      f32x4 z = (f32x4){0.f, 0.f, 0.f, 0.f};
      z = __builtin_amdgcn_mfma_f32_16x16x32_bf16(qf[0], kfr[tf][0], z, 0, 0, 0);
      z = __builtin_amdgcn_mfma_f32_16x16x32_bf16(qf[1], kfr[tf][1], z, 0, 0, 0);
      s[tf] = z;
    }
    __builtin_amdgcn_s_setprio(0);

    short8 vfr[4][2];
#pragma unroll
    for (int df = 0; df < 4; ++df) {
      const int d = df * 16 + lr;
#pragma unroll
      for (int kf = 0; kf < 2; ++kf)
        vfr[df][kf] = *(const short8*)((const char*)Vt + d * 128 +
                                       ((kf * 64 + g * 16) ^ ((d & 7) << 4)));
    }

    // no-max softmax (exp safe in fp32 for LN'd inputs); deferred row-reduce
#pragma unroll
    for (int tf = 0; tf < 4; ++tf)
#pragma unroll
      for (int reg = 0; reg < 4; ++reg) {
        const float p = __expf(s[tf][reg] * 0.125f);
        s[tf][reg] = p;
        ll[reg] += p;
      }

#pragma unroll
    for (int tf = 0; tf < 4; ++tf)
#pragma unroll
      for (int reg = 0; reg < 4; ++reg) {
        const int m = wave * 16 + g * 4 + reg;
        const int t2 = (tf * 16 + lr) * 2;
        *(u16*)((char*)Pl + m * 128 + (t2 ^ ((m & 7) << 4))) = f2bf(s[tf][reg]);
      }
    short8 pa[2];
#pragma unroll
    for (int kf = 0; kf < 2; ++kf)
      pa[kf] = *(const short8*)((const char*)Pl + (wave * 16 + lr) * 128 +
                                ((kf * 64 + g * 16) ^ ((lr & 7) << 4)));
    __builtin_amdgcn_s_setprio(1);
#pragma unroll
    for (int df = 0; df < 4; ++df) {
      o[df] = __builtin_amdgcn_mfma_f32_16x16x32_bf16(pa[0], vfr[df][0], o[df], 0, 0, 0);
      o[df] = __builtin_amdgcn_mfma_f32_16x16x32_bf16(pa[1], vfr[df][1], o[df], 0, 0, 0);
    }
    __builtin_amdgcn_s_setprio(0);
    __syncthreads();
  }

#pragma unroll
  for (int reg = 0; reg < 4; ++reg) {
#pragma unroll
    for (int msk = 1; msk < 16; msk <<= 1) ll[reg] += __shfl_xor(ll[reg], msk);
    const float inv = 1.0f / ll[reg];
    const int row = b * Nn + qb * 128 + wave * 16 + g * 4 + reg;
#pragma unroll
    for (int df = 0; df < 4; ++df) {
      const int col = h * 64 + df * 16 + lr;
      o_out[(size_t)row * 1024 + col] = f2bf(o[df][reg] * inv);
    }
  }
}

// ---------------- launch ----------------
extern "C" void kernel_launch(void* const* d_in, const int* in_sizes, int n_in,
                              void* d_out, int out_size, void* d_ws, size_t ws_size,
                              hipStream_t stream) {
  const float* x    = (const float*)d_in[0];
  const float* qkvw = (const float*)d_in[1];
  const float* qkvb = (const float*)d_in[2];
  const float* apw  = (const float*)d_in[3];
  const float* apb  = (const float*)d_in[4];
  const float* bpw  = (const float*)d_in[5];
  const float* bpb  = (const float*)d_in[6];
  const float* ln1g = (const float*)d_in[7];
  const float* ln1b = (const float*)d_in[8];
  const float* ln2g = (const float*)d_in[9];
  const float* ln2b = (const float*)d_in[10];
  const float* fc1w = (const float*)d_in[11];
  const float* fc1b = (const float*)d_in[12];
  const float* fc2w = (const float*)d_in[13];
  const float* fc2b = (const float*)d_in[14];
  float* out = (float*)d_out;

  char* ws = (char*)d_ws;
  size_t off = 0;
  auto alloc = [&](size_t bytes) {
    char* p = ws + off;
    off += (bytes + 255) & ~(size_t)255;
    return p;
  };
  u16* wqkv  = (u16*)alloc((size_t)3145728 * 2);
  u16* wap   = (u16*)alloc((size_t)1048576 * 2);   // hole, never written/read
  u16* wbp   = (u16*)alloc((size_t)1048576 * 2);
  u16* wfc1  = (u16*)alloc((size_t)4194304 * 2);
  u16* wfc2  = (u16*)alloc((size_t)4194304 * 2);
  u16* xn    = (u16*)alloc((size_t)4194304 * 2);
  u16* qkvbf = (u16*)alloc((size_t)12582912 * 2);
  u16* obuf  = (u16*)alloc((size_t)4194304 * 2);
  float* x2  = (float*)alloc((size_t)4194304 * 4);
  u16* wapT  = (u16*)alloc((size_t)1048576 * 2);   // Wap^T bf16
  u16* wc    = (u16*)alloc((size_t)1048576 * 2);   // Wc = Wbp@Wap bf16
  float* cb  = (float*)alloc(1024 * 4);            // combined bias
  u16* vt    = (u16*)alloc((size_t)4194304 * 2);   // V^T per (b,h): [64][1024]
  u16* ff    = qkvbf;
  (void)wap;

  cvt_all<<<12288, 256, 0, stream>>>(qkvw, bpw, fc1w, fc2w, wqkv);
  transpose_wT<<<256, 256, 0, stream>>>(apw, wapT);
  cbias_k<<<256, 256, 0, stream>>>(apb, bpw, bpb, cb);

  // Wc = Wbp @ Wap  (wc[i,j] = sum_k wbp[i,k] * wapT[j,k])
  gemm64<<<256, 256, 0, stream>>>(wbp, wapT, wc, 1024);

  ln_bf16<<<4096, 256, 0, stream>>>(x, ln1g, ln1b, xn);

  // qkv = xn @ qkv_w^T + b : [4096,3072] -- 256x96 tiles, grid 512 (even)
  gemmS96<false, true><<<512, 512, 0, stream>>>(
      xn, wqkv, qkvb, qkvbf, 4096, 3072, 1024);

  vtrans<<<1024, 256, 0, stream>>>(qkvbf, vt);

  attn_kernel<<<512, 512, 0, stream>>>(qkvbf, vt, obuf);

  // x2 = x + obuf @ Wc^T + cb   (fused attn_proj + blk_proj + residual)
  gemm128t<false, true, false><<<256, 512, 0, stream>>>(
      obuf, wc, cb, x, x2, 4096, 1024, 1024);

  ln_bf16<<<4096, 256, 0, stream>>>(x2, ln2g, ln2b, xn);

  // ff = gelu(h @ fc1_w^T + b) : [4096,4096]
  gemmS<true, true><<<512, 512, 0, stream>>>(
      xn, wfc1, fc1b, ff, 4096, 4096, 1024);

  // out = x2 + ff @ fc2_w^T + b  (fp32)
  gemm128t<false, true, false><<<256, 512, 0, stream>>>(
      ff, wfc2, fc2b, x2, out, 4096, 1024, 4096);
}

// Round 23
// 209.985 us; speedup vs baseline: 1.2894x; 1.0404x over previous
//
#include <hip/hip_runtime.h>

typedef unsigned short u16;
typedef __attribute__((ext_vector_type(8))) short short8;
typedef __attribute__((ext_vector_type(4))) float f32x4;

#define DEVI __device__ __forceinline__

static constexpr int Nn = 1024;   // sequence length
static constexpr int Cc = 1024;   // channels

DEVI u16 f2bf(float f) {
  union { float f; unsigned u; } v; v.f = f;
  unsigned r = v.u + 0x7fffu + ((v.u >> 16) & 1u);
  return (u16)(r >> 16);
}

DEVI void async_ld16(const void* g, void* lds) {
  __builtin_amdgcn_global_load_lds(
      (__attribute__((address_space(1))) void*)g,
      (__attribute__((address_space(3))) void*)lds, 16, 0, 0);
}

// ---------------- fused prep: weight cvt + Wap^T transpose + combined bias -
// blocks [0,12288): fp32->bf16 weight convert (skips unused apw hole)
// blocks [12288,12544): transpose apw -> wapT (bf16)
// blocks [12544,12800): cb[j] = bpb[j] + dot(apb, bpw_row_j)
__global__ __launch_bounds__(256) void prep_k(
    const float* __restrict__ s0, const float* __restrict__ s2,
    const float* __restrict__ s3, const float* __restrict__ s4,
    u16* __restrict__ out,
    const float* __restrict__ apw, u16* __restrict__ wapT,
    const float* __restrict__ apb, const float* __restrict__ bpw,
    const float* __restrict__ bpb, float* __restrict__ cb) {
  __shared__ u16 tile[64][72];
  const int B = blockIdx.x;
  if (B < 12288) {
    const size_t j = ((size_t)B * 256 + threadIdx.x) * 4;
    size_t i; const float* src; size_t lo;
    if (j < 3145728) { i = j; src = s0; lo = 0; }
    else {
      i = j + 1048576;
      if (i < 5242880)      { src = s2; lo = 4194304; }
      else if (i < 9437184) { src = s3; lo = 5242880; }
      else                  { src = s4; lo = 9437184; }
    }
    const float4 v = *(const float4*)&src[i - lo];
    ushort4 o;
    o.x = f2bf(v.x); o.y = f2bf(v.y); o.z = f2bf(v.z); o.w = f2bf(v.w);
    *(ushort4*)&out[i] = o;
  } else if (B < 12544) {
    const int bb = B - 12288;
    const int bx = bb & 15, by = bb >> 4;
    const int tr = threadIdx.x >> 2;
    const int tc4 = (threadIdx.x & 3) * 16;
#pragma unroll
    for (int j = 0; j < 4; ++j) {
      const float4 v = *(const float4*)&apw[(size_t)(by * 64 + tr) * 1024 +
                                            bx * 64 + tc4 + j * 4];
      tile[tc4 + j * 4 + 0][tr] = f2bf(v.x);
      tile[tc4 + j * 4 + 1][tr] = f2bf(v.y);
      tile[tc4 + j * 4 + 2][tr] = f2bf(v.z);
      tile[tc4 + j * 4 + 3][tr] = f2bf(v.w);
    }
    __syncthreads();
#pragma unroll
    for (int j = 0; j < 4; ++j) {
      ushort4 o;
      o.x = tile[tr][tc4 + j * 4 + 0];
      o.y = tile[tr][tc4 + j * 4 + 1];
      o.z = tile[tr][tc4 + j * 4 + 2];
      o.w = tile[tr][tc4 + j * 4 + 3];
      *(ushort4*)&wapT[(size_t)(bx * 64 + tr) * 1024 + by * 64 + tc4 + j * 4] = o;
    }
  } else {
    const int bb = B - 12544;
    const int j = bb * 4 + (threadIdx.x >> 6);
    const int lane = threadIdx.x & 63;
    float s = 0.f;
    for (int k = lane; k < 1024; k += 64) s += apb[k] * bpw[(size_t)j * 1024 + k];
#pragma unroll
    for (int m = 1; m < 64; m <<= 1) s += __shfl_xor(s, m);
    if (lane == 0) cb[j] = s + bpb[j];
  }
}

// ---------------- fused: Wc = Wbp@Wap (64x64 gemm, blocks<256) + LN1 ------
// blocks [0,256): gemm64 over wbp x wapT -> wc (K=1024)
// blocks [256,4352): LayerNorm row (blockIdx-256) of x -> xn (bf16)
__global__ __launch_bounds__(256) void g64ln(
    const u16* __restrict__ A, const u16* __restrict__ W,
    u16* __restrict__ wc,
    const float* __restrict__ x, const float* __restrict__ gg,
    const float* __restrict__ bb, u16* __restrict__ xn) {
  __shared__ __align__(16) u16 As[64 * 64];
  __shared__ __align__(16) u16 Bs[64 * 64];
  __shared__ float ps[4], ps2[4];
  const int tid = threadIdx.x;
  if (blockIdx.x < 256) {
    const int wave = tid >> 6, lane = tid & 63;
    const int g = lane >> 4, lr = lane & 15;
    const int brow = (blockIdx.x >> 4) << 6, bcol = (blockIdx.x & 15) << 6;
    const int srow = lane >> 3;
    const int scg = (lane & 7) ^ srow;
    const int swz = (lr & 7) << 4;

    f32x4 acc[4];
#pragma unroll
    for (int j = 0; j < 4; ++j) acc[j] = (f32x4){0.f, 0.f, 0.f, 0.f};

    for (int k0 = 0; k0 < 1024; k0 += 64) {
#pragma unroll
      for (int u = 0; u < 2; ++u) {
        async_ld16(A + (size_t)(brow + u * 32 + wave * 8 + srow) * 1024 + k0 + scg * 8,
                   (char*)As + u * 4096 + wave * 1024);
        async_ld16(W + (size_t)(bcol + u * 32 + wave * 8 + srow) * 1024 + k0 + scg * 8,
                   (char*)Bs + u * 4096 + wave * 1024);
      }
      __syncthreads();
      short8 af[2], bf[4][2];
#pragma unroll
      for (int kk = 0; kk < 2; ++kk)
        af[kk] = *(const short8*)((char*)As + (wave * 16 + lr) * 128 +
                                  ((kk * 64 + g * 16) ^ swz));
#pragma unroll
      for (int nf = 0; nf < 4; ++nf)
#pragma unroll
        for (int kk = 0; kk < 2; ++kk)
          bf[nf][kk] = *(const short8*)((char*)Bs + (nf * 16 + lr) * 128 +
                                        ((kk * 64 + g * 16) ^ swz));
#pragma unroll
      for (int kk = 0; kk < 2; ++kk)
#pragma unroll
        for (int nf = 0; nf < 4; ++nf)
          acc[nf] = __builtin_amdgcn_mfma_f32_16x16x32_bf16(af[kk], bf[nf][kk],
                                                            acc[nf], 0, 0, 0);
      __syncthreads();
    }
#pragma unroll
    for (int nf = 0; nf < 4; ++nf)
#pragma unroll
      for (int reg = 0; reg < 4; ++reg)
        wc[(size_t)(brow + wave * 16 + g * 4 + reg) * 1024 +
           bcol + nf * 16 + lr] = f2bf(acc[nf][reg]);
  } else {
    const int row = blockIdx.x - 256;
    const float4 v = ((const float4*)(x + (size_t)row * 1024))[tid];
    float s  = v.x + v.y + v.z + v.w;
    float s2 = v.x * v.x + v.y * v.y + v.z * v.z + v.w * v.w;
#pragma unroll
    for (int m = 1; m < 64; m <<= 1) { s += __shfl_xor(s, m); s2 += __shfl_xor(s2, m); }
    const int wave = tid >> 6;
    if ((tid & 63) == 0) { ps[wave] = s; ps2[wave] = s2; }
    __syncthreads();
    s = ps[0] + ps[1] + ps[2] + ps[3];
    s2 = ps2[0] + ps2[1] + ps2[2] + ps2[3];
    const float mu = s * (1.0f / 1024.0f);
    const float var = s2 * (1.0f / 1024.0f) - mu * mu;
    const float rs = rsqrtf(var + 1e-6f);
    const float4 gv = ((const float4*)gg)[tid];
    const float4 bv = ((const float4*)bb)[tid];
    ushort4 o;
    o.x = f2bf((v.x - mu) * rs * gv.x + bv.x);
    o.y = f2bf((v.y - mu) * rs * gv.y + bv.y);
    o.z = f2bf((v.z - mu) * rs * gv.z + bv.z);
    o.w = f2bf((v.w - mu) * rs * gv.w + bv.w);
    ((ushort4*)(xn + (size_t)row * 1024))[tid] = o;
  }
}

// ---------------- V transpose: qkv V-part -> vt[b,h][d][t] bf16 -----------
__global__ __launch_bounds__(256) void vtrans(const u16* __restrict__ qkv,
                                              u16* __restrict__ vt) {
  __shared__ u16 tile[64][72];
  const int bh = blockIdx.x >> 4, tb = blockIdx.x & 15;
  const int b = bh >> 4, h = bh & 15;
  const int t0 = tb * 64;
  const int tid = threadIdx.x;
  const int rr = tid >> 3, c8 = (tid & 7) * 8;
#pragma unroll
  for (int r = 0; r < 2; ++r) {
    const int t = r * 32 + rr;
    const short8 v = *(const short8*)(qkv + (size_t)(b * Nn + t0 + t) * 3072 +
                                      2048 + h * 64 + c8);
#pragma unroll
    for (int j = 0; j < 8; ++j) tile[t][c8 + j] = (u16)v[j];
  }
  __syncthreads();
#pragma unroll
  for (int r = 0; r < 2; ++r) {
    const int d = r * 32 + rr;
    short8 o;
#pragma unroll
    for (int j = 0; j < 8; ++j) o[j] = (short)tile[c8 + j][d];
    *(short8*)(vt + (size_t)(bh * 64 + d) * 1024 + t0 + c8) = o;
  }
}

// ---------------- LayerNorm (row = 1024 fp32) -> bf16 ----------------
__global__ __launch_bounds__(256) void ln_bf16(const float* __restrict__ x,
                                               const float* __restrict__ gg,
                                               const float* __restrict__ bb,
                                               u16* __restrict__ out) {
  const int row = blockIdx.x;
  const float4 v = ((const float4*)(x + (size_t)row * 1024))[threadIdx.x];
  float s  = v.x + v.y + v.z + v.w;
  float s2 = v.x * v.x + v.y * v.y + v.z * v.z + v.w * v.w;
#pragma unroll
  for (int m = 1; m < 64; m <<= 1) { s += __shfl_xor(s, m); s2 += __shfl_xor(s2, m); }
  __shared__ float ps[4], ps2[4];
  const int wave = threadIdx.x >> 6;
  if ((threadIdx.x & 63) == 0) { ps[wave] = s; ps2[wave] = s2; }
  __syncthreads();
  s = ps[0] + ps[1] + ps[2] + ps[3];
  s2 = ps2[0] + ps2[1] + ps2[2] + ps2[3];
  const float mu = s * (1.0f / 1024.0f);
  const float var = s2 * (1.0f / 1024.0f) - mu * mu;
  const float rs = rsqrtf(var + 1e-6f);
  const float4 gv = ((const float4*)gg)[threadIdx.x];
  const float4 bv = ((const float4*)bb)[threadIdx.x];
  ushort4 o;
  o.x = f2bf((v.x - mu) * rs * gv.x + bv.x);
  o.y = f2bf((v.y - mu) * rs * gv.y + bv.y);
  o.z = f2bf((v.z - mu) * rs * gv.z + bv.z);
  o.w = f2bf((v.w - mu) * rs * gv.w + bv.w);
  ((ushort4*)(out + (size_t)row * 1024))[threadIdx.x] = o;
}

// ---------------- GEMM 256x128, BK=64, 8 waves, single-buffer LDS ---------
template <bool GELU_, bool OUTBF>
__global__ __launch_bounds__(512, 4) void gemmS(
    const u16* __restrict__ A, const u16* __restrict__ W,
    const float* __restrict__ bias, void* __restrict__ out,
    int M, int N, int K) {
  __shared__ __align__(16) u16 As[256 * 64];   // 32 KB
  __shared__ __align__(16) u16 Bs[128 * 64];   // 16 KB
  const int tid = threadIdx.x;
  const int wave = tid >> 6, lane = tid & 63;
  const int g = lane >> 4, lr = lane & 15;
  const int wm = wave >> 1, wn = wave & 1;
  const int ntile = N >> 7;
  const int nwg = gridDim.x;
  int bid = blockIdx.x;
  bid = (bid & 7) * (nwg >> 3) + (bid >> 3);   // XCD swizzle (grid % 8 == 0)
  const int brow = (bid / ntile) << 8, bcol = (bid % ntile) << 7;

  const int sru = wave * 8 + (lane >> 3);
  const int scg = (lane & 7) ^ (lane >> 3);
  const int swz = (lr & 7) << 4;

  f32x4 acc[4][4];
#pragma unroll
  for (int i = 0; i < 4; ++i)
#pragma unroll
    for (int j = 0; j < 4; ++j) acc[i][j] = (f32x4){0.f, 0.f, 0.f, 0.f};

  for (int k0 = 0; k0 < K; k0 += 64) {
#pragma unroll
    for (int u = 0; u < 2; ++u)
      async_ld16(W + (size_t)(bcol + u * 64 + sru) * K + k0 + scg * 8,
                 (char*)Bs + u * 8192 + wave * 1024);
#pragma unroll
    for (int u = 0; u < 4; ++u)
      async_ld16(A + (size_t)(brow + u * 64 + sru) * K + k0 + scg * 8,
                 (char*)As + u * 8192 + wave * 1024);
    asm volatile("s_waitcnt vmcnt(0)" ::: "memory");
    __builtin_amdgcn_s_barrier();

    short8 bf[4][2];
#pragma unroll
    for (int nf = 0; nf < 4; ++nf) {
      const int row = wn * 64 + nf * 16 + lr;
#pragma unroll
      for (int kk = 0; kk < 2; ++kk)
        bf[nf][kk] = *(const short8*)((const char*)Bs + row * 128 +
                                      ((kk * 64 + g * 16) ^ swz));
    }
    __builtin_amdgcn_s_setprio(1);
#pragma unroll
    for (int mf = 0; mf < 4; ++mf) {
      short8 af[2];
      const int row = wm * 64 + mf * 16 + lr;
#pragma unroll
      for (int kk = 0; kk < 2; ++kk)
        af[kk] = *(const short8*)((const char*)As + row * 128 +
                                  ((kk * 64 + g * 16) ^ swz));
#pragma unroll
      for (int nf = 0; nf < 4; ++nf)
#pragma unroll
        for (int kk = 0; kk < 2; ++kk)
          acc[mf][nf] = __builtin_amdgcn_mfma_f32_16x16x32_bf16(
              af[kk], bf[nf][kk], acc[mf][nf], 0, 0, 0);
    }
    __builtin_amdgcn_s_setprio(0);
    __builtin_amdgcn_s_barrier();
  }

#pragma unroll
  for (int mf = 0; mf < 4; ++mf)
#pragma unroll
    for (int nf = 0; nf < 4; ++nf) {
      const int cI = bcol + wn * 64 + nf * 16 + lr;
      const float bv = bias[cI];
#pragma unroll
      for (int reg = 0; reg < 4; ++reg) {
        const int r = brow + wm * 64 + mf * 16 + g * 4 + reg;
        float v = acc[mf][nf][reg] + bv;
        if (GELU_) v = 0.5f * v * (1.0f + erff(v * 0.70710678118654752f));
        if (OUTBF) ((u16*)out)[(size_t)r * N + cI] = f2bf(v);
        else       ((float*)out)[(size_t)r * N + cI] = v;
      }
    }
}

// ---------------- GEMM 256x96 (for qkv: grid 16x32 = 512 = even 2/CU) -----
template <bool GELU_, bool OUTBF>
__global__ __launch_bounds__(512, 4) void gemmS96(
    const u16* __restrict__ A, const u16* __restrict__ W,
    const float* __restrict__ bias, void* __restrict__ out,
    int M, int N, int K) {
  __shared__ __align__(16) u16 As[256 * 64];   // 32 KB
  __shared__ __align__(16) u16 Bs[96 * 64];    // 12 KB
  const int tid = threadIdx.x;
  const int wave = tid >> 6, lane = tid & 63;
  const int g = lane >> 4, lr = lane & 15;
  const int wm = wave >> 1, wn = wave & 1;     // 4m x 2n -> wave: 64 x 48
  const int ntile = N / 96;
  const int nwg = gridDim.x;
  int bid = blockIdx.x;
  bid = (bid & 7) * (nwg >> 3) + (bid >> 3);   // XCD swizzle (grid % 8 == 0)
  const int brow = (bid / ntile) << 8;
  const int bcol = (bid % ntile) * 96;

  const int sru = wave * 8 + (lane >> 3);
  const int scg = (lane & 7) ^ (lane >> 3);
  const int swz = (lr & 7) << 4;
  const int brG = tid >> 3;                    // B stage row 0..63
  const int bcg = (tid & 7) ^ (brG & 7);       // pre-swizzled granule

  f32x4 acc[4][3];
#pragma unroll
  for (int i = 0; i < 4; ++i)
#pragma unroll
    for (int j = 0; j < 3; ++j) acc[i][j] = (f32x4){0.f, 0.f, 0.f, 0.f};

  for (int k0 = 0; k0 < K; k0 += 64) {
    async_ld16(W + (size_t)(bcol + brG) * K + k0 + bcg * 8,
               (char*)Bs + tid * 16);
    if (wave < 4)
      async_ld16(W + (size_t)(bcol + 64 + brG) * K + k0 + bcg * 8,
                 (char*)Bs + 8192 + tid * 16);
#pragma unroll
    for (int u = 0; u < 4; ++u)
      async_ld16(A + (size_t)(brow + u * 64 + sru) * K + k0 + scg * 8,
                 (char*)As + u * 8192 + wave * 1024);
    asm volatile("s_waitcnt vmcnt(0)" ::: "memory");
    __builtin_amdgcn_s_barrier();

    short8 bf[3][2];
#pragma unroll
    for (int nf = 0; nf < 3; ++nf) {
      const int row = wn * 48 + nf * 16 + lr;
#pragma unroll
      for (int kk = 0; kk < 2; ++kk)
        bf[nf][kk] = *(const short8*)((const char*)Bs + row * 128 +
                                      ((kk * 64 + g * 16) ^ swz));
    }
    __builtin_amdgcn_s_setprio(1);
#pragma unroll
    for (int mf = 0; mf < 4; ++mf) {
      short8 af[2];
      const int row = wm * 64 + mf * 16 + lr;
#pragma unroll
      for (int kk = 0; kk < 2; ++kk)
        af[kk] = *(const short8*)((const char*)As + row * 128 +
                                  ((kk * 64 + g * 16) ^ swz));
#pragma unroll
      for (int nf = 0; nf < 3; ++nf)
#pragma unroll
        for (int kk = 0; kk < 2; ++kk)
          acc[mf][nf] = __builtin_amdgcn_mfma_f32_16x16x32_bf16(
              af[kk], bf[nf][kk], acc[mf][nf], 0, 0, 0);
    }
    __builtin_amdgcn_s_setprio(0);
    __builtin_amdgcn_s_barrier();
  }

#pragma unroll
  for (int mf = 0; mf < 4; ++mf)
#pragma unroll
    for (int nf = 0; nf < 3; ++nf) {
      const int cI = bcol + wn * 48 + nf * 16 + lr;
      const float bv = bias[cI];
#pragma unroll
      for (int reg = 0; reg < 4; ++reg) {
        const int r = brow + wm * 64 + mf * 16 + g * 4 + reg;
        float v = acc[mf][nf][reg] + bv;
        if (GELU_) v = 0.5f * v * (1.0f + erff(v * 0.70710678118654752f));
        if (OUTBF) ((u16*)out)[(size_t)r * N + cI] = f2bf(v);
        else       ((float*)out)[(size_t)r * N + cI] = v;
      }
    }
}

// ---------------- GEMM 128x128 TRIPLE-buffer (grid 256 ONLY: L2-resident) -
template <bool GELU_, bool RESID, bool OUTBF>
__global__ __launch_bounds__(512, 2) void gemm128t(
    const u16* __restrict__ A, const u16* __restrict__ W,
    const float* __restrict__ bias, const float* __restrict__ resid,
    void* __restrict__ out, int M, int N, int K) {
  __shared__ __align__(16) u16 smem[49152];   // 96 KB: 3 x (A 16K | B 16K)
  const int tid = threadIdx.x;
  const int wave = tid >> 6, lane = tid & 63;
  const int g = lane >> 4, lr = lane & 15;
  const int kg = wave & 1, ws = wave >> 1;
  const int wm = ws >> 1, wn = ws & 1;
  const int ntile = N >> 7;
  const int nwg = gridDim.x;
  int bid = blockIdx.x;
  bid = (bid & 7) * (nwg >> 3) + (bid >> 3);   // grid % 8 == 0
  const int brow = (bid / ntile) << 7, bcol = (bid % ntile) << 7;

  const int sru = wave * 8 + (lane >> 3);
  const int scg = (lane & 7) ^ (lane >> 3);
  const int NT = K >> 6;

  f32x4 acc[4][4];
#pragma unroll
  for (int i = 0; i < 4; ++i)
#pragma unroll
    for (int j = 0; j < 4; ++j) acc[i][j] = (f32x4){0.f, 0.f, 0.f, 0.f};

  auto STAGE = [&](int b, int kt) {
    char* base = (char*)smem + b * 32768;
#pragma unroll
    for (int u = 0; u < 2; ++u)
      async_ld16(W + (size_t)(bcol + u * 64 + sru) * K + (size_t)kt * 64 + scg * 8,
                 base + 16384 + u * 8192 + wave * 1024);
#pragma unroll
    for (int u = 0; u < 2; ++u)
      async_ld16(A + (size_t)(brow + u * 64 + sru) * K + (size_t)kt * 64 + scg * 8,
                 base + u * 8192 + wave * 1024);
  };

  const int colb = kg * 64 + g * 16;
  const int swz = (lr & 7) << 4;

  STAGE(0, 0);
  STAGE(1, 1 < NT ? 1 : 0);
  asm volatile("s_waitcnt vmcnt(4)" ::: "memory");
  __builtin_amdgcn_s_barrier();

  for (int t = 0; t < NT; ++t) {
    const int b = t % 3;
    const char* Ab = (const char*)smem + b * 32768;
    const char* Bb = Ab + 16384;

    short8 bf[4], af[4];
#pragma unroll
    for (int nf = 0; nf < 4; ++nf)
      bf[nf] = *(const short8*)(Bb + (wn * 64 + nf * 16 + lr) * 128 +
                                (colb ^ swz));
#pragma unroll
    for (int mf = 0; mf < 2; ++mf) {
      af[mf]     = *(const short8*)(Ab + (wm * 32 + mf * 16 + lr) * 128 +
                                    (colb ^ swz));
      af[mf + 2] = *(const short8*)(Ab + (64 + wm * 32 + mf * 16 + lr) * 128 +
                                    (colb ^ swz));
    }
    {
      const int pt = (t + 2 < NT) ? t + 2 : NT - 1;
      STAGE((t + 2) % 3, pt);
    }
    __builtin_amdgcn_s_setprio(1);
#pragma unroll
    for (int mf = 0; mf < 4; ++mf)
#pragma unroll
      for (int nf = 0; nf < 4; ++nf)
        acc[mf][nf] = __builtin_amdgcn_mfma_f32_16x16x32_bf16(
            af[mf], bf[nf], acc[mf][nf], 0, 0, 0);
    __builtin_amdgcn_s_setprio(0);
    asm volatile("s_waitcnt vmcnt(4)" ::: "memory");
    __builtin_amdgcn_s_barrier();
  }

  asm volatile("s_waitcnt vmcnt(0)" ::: "memory");
  __syncthreads();
  float* pr = (float*)smem + (size_t)((wm << 1) | wn) * 4096;
  if (kg == 1) {
#pragma unroll
    for (int mf = 0; mf < 4; ++mf)
#pragma unroll
      for (int nf = 0; nf < 4; ++nf)
#pragma unroll
        for (int reg = 0; reg < 4; ++reg) {
          const int lrow = mf * 16 + g * 4 + reg;
          const int w = lrow * 64 +
                        ((nf * 16 + lr) ^ (g << 2) ^ ((g & 1) << 4));
          pr[w] = acc[mf][nf][reg];
        }
  }
  __syncthreads();
  if (kg == 0) {
#pragma unroll
    for (int mf = 0; mf < 4; ++mf) {
      const int rb = brow + ((mf < 2) ? wm * 32 + mf * 16
                                      : 64 + wm * 32 + (mf - 2) * 16);
#pragma unroll
      for (int nf = 0; nf < 4; ++nf) {
        const int cI = bcol + wn * 64 + nf * 16 + lr;
        const float bv = bias[cI];
#pragma unroll
        for (int reg = 0; reg < 4; ++reg) {
          const int lrow = mf * 16 + g * 4 + reg;
          const int w = lrow * 64 +
                        ((nf * 16 + lr) ^ (g << 2) ^ ((g & 1) << 4));
          const int r = rb + g * 4 + reg;
          float v = acc[mf][nf][reg] + pr[w] + bv;
          if (GELU_) v = 0.5f * v * (1.0f + erff(v * 0.70710678118654752f));
          if (RESID) v += resid[(size_t)r * N + cI];
          if (OUTBF) ((u16*)out)[(size_t)r * N + cI] = f2bf(v);
          else       ((float*)out)[(size_t)r * N + cI] = v;
        }
      }
    }
  }
}

// ---------------- Flash attention: 8 waves, 128 q-rows/block (r18 best) ---
__global__ __launch_bounds__(512) void attn_kernel(const u16* __restrict__ qkv,
                                                   const u16* __restrict__ vt,
                                                   u16* __restrict__ o_out) {
  const int D = blockIdx.x;
  const int bh = (D & 7) + 8 * (D >> 6);   // same (b,h) -> same XCD
  const int qb = (D >> 3) & 7;
  const int b = bh >> 4, h = bh & 15;
  const int tid = threadIdx.x, wave = tid >> 6, lane = tid & 63;
  const int g = lane >> 4, lr = lane & 15;
  const u16* qg = qkv + (size_t)b * Nn * 3072 + h * 64;
  const u16* kg = qg + 1024;
  const u16* vgt = vt + (size_t)bh * 64 * 1024;

  __shared__ __align__(16) u16 Kl[64 * 64];
  __shared__ __align__(16) u16 Vt[64 * 64];
  __shared__ __align__(16) u16 Pl[128 * 64];

  const int q0 = qb * 128 + wave * 16;
  short8 qf[2];
#pragma unroll
  for (int kf = 0; kf < 2; ++kf)
    qf[kf] = *(const short8*)(qg + (size_t)(q0 + lr) * 3072 + kf * 32 + g * 8);

  f32x4 o[4];
  float ll[4];
#pragma unroll
  for (int df = 0; df < 4; ++df) o[df] = (f32x4){0.f, 0.f, 0.f, 0.f};
#pragma unroll
  for (int r = 0; r < 4; ++r) ll[r] = 0.f;

  const int sc = wave * 64 + lane;             // granule id 0..511
  const int st = sc >> 3;                      // tile row 0..63
  const int sob = ((sc & 7) << 4) ^ ((st & 7) << 4);

  for (int t0 = 0; t0 < Nn; t0 += 64) {
    async_ld16(kg + (size_t)(t0 + st) * 3072 + (sob >> 1),
               (char*)Kl + (size_t)(wave * 64) * 16);
    async_ld16(vgt + (size_t)st * 1024 + t0 + (sob >> 1),
               (char*)Vt + (size_t)(wave * 64) * 16);
    __syncthreads();

    short8 kfr[4][2];
#pragma unroll
    for (int tf = 0; tf < 4; ++tf) {
      const int t = tf * 16 + lr;
#pragma unroll
      for (int kf = 0; kf < 2; ++kf)
        kfr[tf][kf] = *(const short8*)((const char*)Kl + t * 128 +
                                       ((kf * 64 + g * 16) ^ ((t & 7) << 4)));
    }
    f32x4 s[4];
    __builtin_amdgcn_s_setprio(1);
#pragma unroll
    for (int tf = 0; tf < 4; ++tf) {
      f32x4 z = (f32x4){0.f, 0.f, 0.f, 0.f};
      z = __builtin_amdgcn_mfma_f32_16x16x32_bf16(qf[0], kfr[tf][0], z, 0, 0, 0);
      z = __builtin_amdgcn_mfma_f32_16x16x32_bf16(qf[1], kfr[tf][1], z, 0, 0, 0);
      s[tf] = z;
    }
    __builtin_amdgcn_s_setprio(0);

    short8 vfr[4][2];
#pragma unroll
    for (int df = 0; df < 4; ++df) {
      const int d = df * 16 + lr;
#pragma unroll
      for (int kf = 0; kf < 2; ++kf)
        vfr[df][kf] = *(const short8*)((const char*)Vt + d * 128 +
                                       ((kf * 64 + g * 16) ^ ((d & 7) << 4)));
    }

    // no-max softmax (exp safe in fp32 for LN'd inputs); deferred row-reduce
#pragma unroll
    for (int tf = 0; tf < 4; ++tf)
#pragma unroll
      for (int reg = 0; reg < 4; ++reg) {
        const float p = __expf(s[tf][reg] * 0.125f);
        s[tf][reg] = p;
        ll[reg] += p;
      }

#pragma unroll
    for (int tf = 0; tf < 4; ++tf)
#pragma unroll
      for (int reg = 0; reg < 4; ++reg) {
        const int m = wave * 16 + g * 4 + reg;
        const int t2 = (tf * 16 + lr) * 2;
        *(u16*)((char*)Pl + m * 128 + (t2 ^ ((m & 7) << 4))) = f2bf(s[tf][reg]);
      }
    short8 pa[2];
#pragma unroll
    for (int kf = 0; kf < 2; ++kf)
      pa[kf] = *(const short8*)((const char*)Pl + (wave * 16 + lr) * 128 +
                                ((kf * 64 + g * 16) ^ ((lr & 7) << 4)));
    __builtin_amdgcn_s_setprio(1);
#pragma unroll
    for (int df = 0; df < 4; ++df) {
      o[df] = __builtin_amdgcn_mfma_f32_16x16x32_bf16(pa[0], vfr[df][0], o[df], 0, 0, 0);
      o[df] = __builtin_amdgcn_mfma_f32_16x16x32_bf16(pa[1], vfr[df][1], o[df], 0, 0, 0);
    }
    __builtin_amdgcn_s_setprio(0);
    __syncthreads();
  }

#pragma unroll
  for (int reg = 0; reg < 4; ++reg) {
#pragma unroll
    for (int msk = 1; msk < 16; msk <<= 1) ll[reg] += __shfl_xor(ll[reg], msk);
    const float inv = 1.0f / ll[reg];
    const int row = b * Nn + qb * 128 + wave * 16 + g * 4 + reg;
#pragma unroll
    for (int df = 0; df < 4; ++df) {
      const int col = h * 64 + df * 16 + lr;
      o_out[(size_t)row * 1024 + col] = f2bf(o[df][reg] * inv);
    }
  }
}

// ---------------- launch ----------------
extern "C" void kernel_launch(void* const* d_in, const int* in_sizes, int n_in,
                              void* d_out, int out_size, void* d_ws, size_t ws_size,
                              hipStream_t stream) {
  const float* x    = (const float*)d_in[0];
  const float* qkvw = (const float*)d_in[1];
  const float* qkvb = (const float*)d_in[2];
  const float* apw  = (const float*)d_in[3];
  const float* apb  = (const float*)d_in[4];
  const float* bpw  = (const float*)d_in[5];
  const float* bpb  = (const float*)d_in[6];
  const float* ln1g = (const float*)d_in[7];
  const float* ln1b = (const float*)d_in[8];
  const float* ln2g = (const float*)d_in[9];
  const float* ln2b = (const float*)d_in[10];
  const float* fc1w = (const float*)d_in[11];
  const float* fc1b = (const float*)d_in[12];
  const float* fc2w = (const float*)d_in[13];
  const float* fc2b = (const float*)d_in[14];
  float* out = (float*)d_out;

  char* ws = (char*)d_ws;
  size_t off = 0;
  auto alloc = [&](size_t bytes) {
    char* p = ws + off;
    off += (bytes + 255) & ~(size_t)255;
    return p;
  };
  u16* wqkv  = (u16*)alloc((size_t)3145728 * 2);
  u16* wap   = (u16*)alloc((size_t)1048576 * 2);   // hole, never written/read
  u16* wbp   = (u16*)alloc((size_t)1048576 * 2);
  u16* wfc1  = (u16*)alloc((size_t)4194304 * 2);
  u16* wfc2  = (u16*)alloc((size_t)4194304 * 2);
  u16* xn    = (u16*)alloc((size_t)4194304 * 2);
  u16* qkvbf = (u16*)alloc((size_t)12582912 * 2);
  u16* obuf  = (u16*)alloc((size_t)4194304 * 2);
  float* x2  = (float*)alloc((size_t)4194304 * 4);
  u16* wapT  = (u16*)alloc((size_t)1048576 * 2);   // Wap^T bf16
  u16* wc    = (u16*)alloc((size_t)1048576 * 2);   // Wc = Wbp@Wap bf16
  float* cb  = (float*)alloc(1024 * 4);            // combined bias
  u16* vt    = (u16*)alloc((size_t)4194304 * 2);   // V^T per (b,h): [64][1024]
  u16* ff    = qkvbf;
  (void)wap;

  // prep: weight cvt (12288 blks) + Wap^T transpose (256) + cbias (256)
  prep_k<<<12800, 256, 0, stream>>>(qkvw, bpw, fc1w, fc2w, wqkv,
                                    apw, wapT, apb, bpw, bpb, cb);

  // Wc = Wbp @ Wap (256 blks) + LN1 (4096 blks), fused
  g64ln<<<4352, 256, 0, stream>>>(wbp, wapT, wc, x, ln1g, ln1b, xn);

  // qkv = xn @ qkv_w^T + b : [4096,3072] -- 256x96 tiles, grid 512 (even)
  gemmS96<false, true><<<512, 512, 0, stream>>>(
      xn, wqkv, qkvb, qkvbf, 4096, 3072, 1024);

  vtrans<<<1024, 256, 0, stream>>>(qkvbf, vt);

  attn_kernel<<<512, 512, 0, stream>>>(qkvbf, vt, obuf);

  // x2 = x + obuf @ Wc^T + cb   (fused attn_proj + blk_proj + residual)
  gemm128t<false, true, false><<<256, 512, 0, stream>>>(
      obuf, wc, cb, x, x2, 4096, 1024, 1024);

  ln_bf16<<<4096, 256, 0, stream>>>(x2, ln2g, ln2b, xn);

  // ff = gelu(h @ fc1_w^T + b) : [4096,4096]
  gemmS<true, true><<<512, 512, 0, stream>>>(
      xn, wfc1, fc1b, ff, 4096, 4096, 1024);

  // out = x2 + ff @ fc2_w^T + b  (fp32)
  gemm128t<false, true, false><<<256, 512, 0, stream>>>(
      ff, wfc2, fc2b, x2, out, 4096, 1024, 4096);
}

// Round 24
// 207.206 us; speedup vs baseline: 1.3067x; 1.0134x over previous
//
#include <hip/hip_runtime.h>

typedef unsigned short u16;
typedef __attribute__((ext_vector_type(8))) short short8;
typedef __attribute__((ext_vector_type(4))) float f32x4;

#define DEVI __device__ __forceinline__

static constexpr int Nn = 1024;   // sequence length
static constexpr int Cc = 1024;   // channels

DEVI u16 f2bf(float f) {
  union { float f; unsigned u; } v; v.f = f;
  unsigned r = v.u + 0x7fffu + ((v.u >> 16) & 1u);
  return (u16)(r >> 16);
}

DEVI void async_ld16(const void* g, void* lds) {
  __builtin_amdgcn_global_load_lds(
      (__attribute__((address_space(1))) void*)g,
      (__attribute__((address_space(3))) void*)lds, 16, 0, 0);
}

// ---------------- fused prep: weight cvt + Wap^T transpose + combined bias -
__global__ __launch_bounds__(256) void prep_k(
    const float* __restrict__ s0, const float* __restrict__ s2,
    const float* __restrict__ s3, const float* __restrict__ s4,
    u16* __restrict__ out,
    const float* __restrict__ apw, u16* __restrict__ wapT,
    const float* __restrict__ apb, const float* __restrict__ bpw,
    const float* __restrict__ bpb, float* __restrict__ cb) {
  __shared__ u16 tile[64][72];
  const int B = blockIdx.x;
  if (B < 12288) {
    const size_t j = ((size_t)B * 256 + threadIdx.x) * 4;
    size_t i; const float* src; size_t lo;
    if (j < 3145728) { i = j; src = s0; lo = 0; }
    else {
      i = j + 1048576;
      if (i < 5242880)      { src = s2; lo = 4194304; }
      else if (i < 9437184) { src = s3; lo = 5242880; }
      else                  { src = s4; lo = 9437184; }
    }
    const float4 v = *(const float4*)&src[i - lo];
    ushort4 o;
    o.x = f2bf(v.x); o.y = f2bf(v.y); o.z = f2bf(v.z); o.w = f2bf(v.w);
    *(ushort4*)&out[i] = o;
  } else if (B < 12544) {
    const int bb = B - 12288;
    const int bx = bb & 15, by = bb >> 4;
    const int tr = threadIdx.x >> 2;
    const int tc4 = (threadIdx.x & 3) * 16;
#pragma unroll
    for (int j = 0; j < 4; ++j) {
      const float4 v = *(const float4*)&apw[(size_t)(by * 64 + tr) * 1024 +
                                            bx * 64 + tc4 + j * 4];
      tile[tc4 + j * 4 + 0][tr] = f2bf(v.x);
      tile[tc4 + j * 4 + 1][tr] = f2bf(v.y);
      tile[tc4 + j * 4 + 2][tr] = f2bf(v.z);
      tile[tc4 + j * 4 + 3][tr] = f2bf(v.w);
    }
    __syncthreads();
#pragma unroll
    for (int j = 0; j < 4; ++j) {
      ushort4 o;
      o.x = tile[tr][tc4 + j * 4 + 0];
      o.y = tile[tr][tc4 + j * 4 + 1];
      o.z = tile[tr][tc4 + j * 4 + 2];
      o.w = tile[tr][tc4 + j * 4 + 3];
      *(ushort4*)&wapT[(size_t)(bx * 64 + tr) * 1024 + by * 64 + tc4 + j * 4] = o;
    }
  } else {
    const int bb = B - 12544;
    const int j = bb * 4 + (threadIdx.x >> 6);
    const int lane = threadIdx.x & 63;
    float s = 0.f;
    for (int k = lane; k < 1024; k += 64) s += apb[k] * bpw[(size_t)j * 1024 + k];
#pragma unroll
    for (int m = 1; m < 64; m <<= 1) s += __shfl_xor(s, m);
    if (lane == 0) cb[j] = s + bpb[j];
  }
}

// ---------------- fused: Wc = Wbp@Wap (64x64 gemm, blocks<256) + LN1 ------
__global__ __launch_bounds__(256) void g64ln(
    const u16* __restrict__ A, const u16* __restrict__ W,
    u16* __restrict__ wc,
    const float* __restrict__ x, const float* __restrict__ gg,
    const float* __restrict__ bb, u16* __restrict__ xn) {
  __shared__ __align__(16) u16 As[64 * 64];
  __shared__ __align__(16) u16 Bs[64 * 64];
  __shared__ float ps[4], ps2[4];
  const int tid = threadIdx.x;
  if (blockIdx.x < 256) {
    const int wave = tid >> 6, lane = tid & 63;
    const int g = lane >> 4, lr = lane & 15;
    const int brow = (blockIdx.x >> 4) << 6, bcol = (blockIdx.x & 15) << 6;
    const int srow = lane >> 3;
    const int scg = (lane & 7) ^ srow;
    const int swz = (lr & 7) << 4;

    f32x4 acc[4];
#pragma unroll
    for (int j = 0; j < 4; ++j) acc[j] = (f32x4){0.f, 0.f, 0.f, 0.f};

    for (int k0 = 0; k0 < 1024; k0 += 64) {
#pragma unroll
      for (int u = 0; u < 2; ++u) {
        async_ld16(A + (size_t)(brow + u * 32 + wave * 8 + srow) * 1024 + k0 + scg * 8,
                   (char*)As + u * 4096 + wave * 1024);
        async_ld16(W + (size_t)(bcol + u * 32 + wave * 8 + srow) * 1024 + k0 + scg * 8,
                   (char*)Bs + u * 4096 + wave * 1024);
      }
      __syncthreads();
      short8 af[2], bf[4][2];
#pragma unroll
      for (int kk = 0; kk < 2; ++kk)
        af[kk] = *(const short8*)((char*)As + (wave * 16 + lr) * 128 +
                                  ((kk * 64 + g * 16) ^ swz));
#pragma unroll
      for (int nf = 0; nf < 4; ++nf)
#pragma unroll
        for (int kk = 0; kk < 2; ++kk)
          bf[nf][kk] = *(const short8*)((char*)Bs + (nf * 16 + lr) * 128 +
                                        ((kk * 64 + g * 16) ^ swz));
#pragma unroll
      for (int kk = 0; kk < 2; ++kk)
#pragma unroll
        for (int nf = 0; nf < 4; ++nf)
          acc[nf] = __builtin_amdgcn_mfma_f32_16x16x32_bf16(af[kk], bf[nf][kk],
                                                            acc[nf], 0, 0, 0);
      __syncthreads();
    }
#pragma unroll
    for (int nf = 0; nf < 4; ++nf)
#pragma unroll
      for (int reg = 0; reg < 4; ++reg)
        wc[(size_t)(brow + wave * 16 + g * 4 + reg) * 1024 +
           bcol + nf * 16 + lr] = f2bf(acc[nf][reg]);
  } else {
    const int row = blockIdx.x - 256;
    const float4 v = ((const float4*)(x + (size_t)row * 1024))[tid];
    float s  = v.x + v.y + v.z + v.w;
    float s2 = v.x * v.x + v.y * v.y + v.z * v.z + v.w * v.w;
#pragma unroll
    for (int m = 1; m < 64; m <<= 1) { s += __shfl_xor(s, m); s2 += __shfl_xor(s2, m); }
    const int wave = tid >> 6;
    if ((tid & 63) == 0) { ps[wave] = s; ps2[wave] = s2; }
    __syncthreads();
    s = ps[0] + ps[1] + ps[2] + ps[3];
    s2 = ps2[0] + ps2[1] + ps2[2] + ps2[3];
    const float mu = s * (1.0f / 1024.0f);
    const float var = s2 * (1.0f / 1024.0f) - mu * mu;
    const float rs = rsqrtf(var + 1e-6f);
    const float4 gv = ((const float4*)gg)[tid];
    const float4 bv = ((const float4*)bb)[tid];
    ushort4 o;
    o.x = f2bf((v.x - mu) * rs * gv.x + bv.x);
    o.y = f2bf((v.y - mu) * rs * gv.y + bv.y);
    o.z = f2bf((v.z - mu) * rs * gv.z + bv.z);
    o.w = f2bf((v.w - mu) * rs * gv.w + bv.w);
    ((ushort4*)(xn + (size_t)row * 1024))[tid] = o;
  }
}

// ---------------- LayerNorm (row = 1024 fp32) -> bf16 ----------------
__global__ __launch_bounds__(256) void ln_bf16(const float* __restrict__ x,
                                               const float* __restrict__ gg,
                                               const float* __restrict__ bb,
                                               u16* __restrict__ out) {
  const int row = blockIdx.x;
  const float4 v = ((const float4*)(x + (size_t)row * 1024))[threadIdx.x];
  float s  = v.x + v.y + v.z + v.w;
  float s2 = v.x * v.x + v.y * v.y + v.z * v.z + v.w * v.w;
#pragma unroll
  for (int m = 1; m < 64; m <<= 1) { s += __shfl_xor(s, m); s2 += __shfl_xor(s2, m); }
  __shared__ float ps[4], ps2[4];
  const int wave = threadIdx.x >> 6;
  if ((threadIdx.x & 63) == 0) { ps[wave] = s; ps2[wave] = s2; }
  __syncthreads();
  s = ps[0] + ps[1] + ps[2] + ps[3];
  s2 = ps2[0] + ps2[1] + ps2[2] + ps2[3];
  const float mu = s * (1.0f / 1024.0f);
  const float var = s2 * (1.0f / 1024.0f) - mu * mu;
  const float rs = rsqrtf(var + 1e-6f);
  const float4 gv = ((const float4*)gg)[threadIdx.x];
  const float4 bv = ((const float4*)bb)[threadIdx.x];
  ushort4 o;
  o.x = f2bf((v.x - mu) * rs * gv.x + bv.x);
  o.y = f2bf((v.y - mu) * rs * gv.y + bv.y);
  o.z = f2bf((v.z - mu) * rs * gv.z + bv.z);
  o.w = f2bf((v.w - mu) * rs * gv.w + bv.w);
  ((ushort4*)(out + (size_t)row * 1024))[threadIdx.x] = o;
}

// ---------------- GEMM 256x128, BK=64, 8 waves, single-buffer LDS ---------
template <bool GELU_, bool OUTBF>
__global__ __launch_bounds__(512, 4) void gemmS(
    const u16* __restrict__ A, const u16* __restrict__ W,
    const float* __restrict__ bias, void* __restrict__ out,
    int M, int N, int K) {
  __shared__ __align__(16) u16 As[256 * 64];   // 32 KB
  __shared__ __align__(16) u16 Bs[128 * 64];   // 16 KB
  const int tid = threadIdx.x;
  const int wave = tid >> 6, lane = tid & 63;
  const int g = lane >> 4, lr = lane & 15;
  const int wm = wave >> 1, wn = wave & 1;
  const int ntile = N >> 7;
  const int nwg = gridDim.x;
  int bid = blockIdx.x;
  bid = (bid & 7) * (nwg >> 3) + (bid >> 3);   // XCD swizzle (grid % 8 == 0)
  const int brow = (bid / ntile) << 8, bcol = (bid % ntile) << 7;

  const int sru = wave * 8 + (lane >> 3);
  const int scg = (lane & 7) ^ (lane >> 3);
  const int swz = (lr & 7) << 4;

  f32x4 acc[4][4];
#pragma unroll
  for (int i = 0; i < 4; ++i)
#pragma unroll
    for (int j = 0; j < 4; ++j) acc[i][j] = (f32x4){0.f, 0.f, 0.f, 0.f};

  for (int k0 = 0; k0 < K; k0 += 64) {
#pragma unroll
    for (int u = 0; u < 2; ++u)
      async_ld16(W + (size_t)(bcol + u * 64 + sru) * K + k0 + scg * 8,
                 (char*)Bs + u * 8192 + wave * 1024);
#pragma unroll
    for (int u = 0; u < 4; ++u)
      async_ld16(A + (size_t)(brow + u * 64 + sru) * K + k0 + scg * 8,
                 (char*)As + u * 8192 + wave * 1024);
    asm volatile("s_waitcnt vmcnt(0)" ::: "memory");
    __builtin_amdgcn_s_barrier();

    short8 bf[4][2];
#pragma unroll
    for (int nf = 0; nf < 4; ++nf) {
      const int row = wn * 64 + nf * 16 + lr;
#pragma unroll
      for (int kk = 0; kk < 2; ++kk)
        bf[nf][kk] = *(const short8*)((const char*)Bs + row * 128 +
                                      ((kk * 64 + g * 16) ^ swz));
    }
    __builtin_amdgcn_s_setprio(1);
#pragma unroll
    for (int mf = 0; mf < 4; ++mf) {
      short8 af[2];
      const int row = wm * 64 + mf * 16 + lr;
#pragma unroll
      for (int kk = 0; kk < 2; ++kk)
        af[kk] = *(const short8*)((const char*)As + row * 128 +
                                  ((kk * 64 + g * 16) ^ swz));
#pragma unroll
      for (int nf = 0; nf < 4; ++nf)
#pragma unroll
        for (int kk = 0; kk < 2; ++kk)
          acc[mf][nf] = __builtin_amdgcn_mfma_f32_16x16x32_bf16(
              af[kk], bf[nf][kk], acc[mf][nf], 0, 0, 0);
    }
    __builtin_amdgcn_s_setprio(0);
    __builtin_amdgcn_s_barrier();
  }

#pragma unroll
  for (int mf = 0; mf < 4; ++mf)
#pragma unroll
    for (int nf = 0; nf < 4; ++nf) {
      const int cI = bcol + wn * 64 + nf * 16 + lr;
      const float bv = bias[cI];
#pragma unroll
      for (int reg = 0; reg < 4; ++reg) {
        const int r = brow + wm * 64 + mf * 16 + g * 4 + reg;
        float v = acc[mf][nf][reg] + bv;
        if (GELU_) v = 0.5f * v * (1.0f + erff(v * 0.70710678118654752f));
        if (OUTBF) ((u16*)out)[(size_t)r * N + cI] = f2bf(v);
        else       ((float*)out)[(size_t)r * N + cI] = v;
      }
    }
}

// ---------------- GEMM 256x96 for qkv (grid 512), V written DIRECT to vt --
// Q/K columns (cI < 2048) -> qkvbf as before.  V columns (cI >= 2048) are
// read ONLY as vt[bh][d][t], so the epilogue writes them transposed there
// and skips qkvbf entirely (deletes the vtrans kernel + 24 MB of traffic).
// Per-16-col run the K/V predicate, h are wave-uniform (2048%16==0, runs
// never cross a 64-col boundary since 16|64).
__global__ __launch_bounds__(512, 4) void gemmS96(
    const u16* __restrict__ A, const u16* __restrict__ W,
    const float* __restrict__ bias, u16* __restrict__ out,
    u16* __restrict__ vt, int M, int N, int K) {
  __shared__ __align__(16) u16 As[256 * 64];   // 32 KB
  __shared__ __align__(16) u16 Bs[96 * 64];    // 12 KB
  const int tid = threadIdx.x;
  const int wave = tid >> 6, lane = tid & 63;
  const int g = lane >> 4, lr = lane & 15;
  const int wm = wave >> 1, wn = wave & 1;     // 4m x 2n -> wave: 64 x 48
  const int ntile = N / 96;
  const int nwg = gridDim.x;
  int bid = blockIdx.x;
  bid = (bid & 7) * (nwg >> 3) + (bid >> 3);   // XCD swizzle (grid % 8 == 0)
  const int brow = (bid / ntile) << 8;
  const int bcol = (bid % ntile) * 96;

  const int sru = wave * 8 + (lane >> 3);
  const int scg = (lane & 7) ^ (lane >> 3);
  const int swz = (lr & 7) << 4;
  const int brG = tid >> 3;                    // B stage row 0..63
  const int bcg = (tid & 7) ^ (brG & 7);       // pre-swizzled granule

  f32x4 acc[4][3];
#pragma unroll
  for (int i = 0; i < 4; ++i)
#pragma unroll
    for (int j = 0; j < 3; ++j) acc[i][j] = (f32x4){0.f, 0.f, 0.f, 0.f};

  for (int k0 = 0; k0 < K; k0 += 64) {
    async_ld16(W + (size_t)(bcol + brG) * K + k0 + bcg * 8,
               (char*)Bs + tid * 16);
    if (wave < 4)
      async_ld16(W + (size_t)(bcol + 64 + brG) * K + k0 + bcg * 8,
                 (char*)Bs + 8192 + tid * 16);
#pragma unroll
    for (int u = 0; u < 4; ++u)
      async_ld16(A + (size_t)(brow + u * 64 + sru) * K + k0 + scg * 8,
                 (char*)As + u * 8192 + wave * 1024);
    asm volatile("s_waitcnt vmcnt(0)" ::: "memory");
    __builtin_amdgcn_s_barrier();

    short8 bf[3][2];
#pragma unroll
    for (int nf = 0; nf < 3; ++nf) {
      const int row = wn * 48 + nf * 16 + lr;
#pragma unroll
      for (int kk = 0; kk < 2; ++kk)
        bf[nf][kk] = *(const short8*)((const char*)Bs + row * 128 +
                                      ((kk * 64 + g * 16) ^ swz));
    }
    __builtin_amdgcn_s_setprio(1);
#pragma unroll
    for (int mf = 0; mf < 4; ++mf) {
      short8 af[2];
      const int row = wm * 64 + mf * 16 + lr;
#pragma unroll
      for (int kk = 0; kk < 2; ++kk)
        af[kk] = *(const short8*)((const char*)As + row * 128 +
                                  ((kk * 64 + g * 16) ^ swz));
#pragma unroll
      for (int nf = 0; nf < 3; ++nf)
#pragma unroll
        for (int kk = 0; kk < 2; ++kk)
          acc[mf][nf] = __builtin_amdgcn_mfma_f32_16x16x32_bf16(
              af[kk], bf[nf][kk], acc[mf][nf], 0, 0, 0);
    }
    __builtin_amdgcn_s_setprio(0);
    __builtin_amdgcn_s_barrier();
  }

#pragma unroll
  for (int nf = 0; nf < 3; ++nf) {
    const int cb0 = bcol + wn * 48 + nf * 16;   // 16-aligned, wave-uniform run
    const int cI = cb0 + lr;
    const float bv = bias[cI];
    if (cb0 < 2048) {
      // Q/K: normal row-major write to qkvbf
#pragma unroll
      for (int mf = 0; mf < 4; ++mf)
#pragma unroll
        for (int reg = 0; reg < 4; ++reg) {
          const int r = brow + wm * 64 + mf * 16 + g * 4 + reg;
          out[(size_t)r * N + cI] = f2bf(acc[mf][nf][reg] + bv);
        }
    } else {
      // V: transposed write into vt[bh][d][t]
      const int dg0 = cb0 - 2048;
      const int hh = dg0 >> 6;                  // wave-uniform (run ⊂ 64-block)
      const int d = (dg0 & 63) + lr;            // per-lane vt row
#pragma unroll
      for (int mf = 0; mf < 4; ++mf)
#pragma unroll
        for (int reg = 0; reg < 4; ++reg) {
          const int r = brow + wm * 64 + mf * 16 + g * 4 + reg;
          const int b = r >> 10, t = r & 1023;
          vt[(size_t)(((b << 4) + hh) * 64 + d) * 1024 + t] =
              f2bf(acc[mf][nf][reg] + bv);
        }
    }
  }
}

// ---------------- GEMM 128x128 TRIPLE-buffer (grid 256 ONLY: L2-resident) -
template <bool GELU_, bool RESID, bool OUTBF>
__global__ __launch_bounds__(512, 2) void gemm128t(
    const u16* __restrict__ A, const u16* __restrict__ W,
    const float* __restrict__ bias, const float* __restrict__ resid,
    void* __restrict__ out, int M, int N, int K) {
  __shared__ __align__(16) u16 smem[49152];   // 96 KB: 3 x (A 16K | B 16K)
  const int tid = threadIdx.x;
  const int wave = tid >> 6, lane = tid & 63;
  const int g = lane >> 4, lr = lane & 15;
  const int kg = wave & 1, ws = wave >> 1;
  const int wm = ws >> 1, wn = ws & 1;
  const int ntile = N >> 7;
  const int nwg = gridDim.x;
  int bid = blockIdx.x;
  bid = (bid & 7) * (nwg >> 3) + (bid >> 3);   // grid % 8 == 0
  const int brow = (bid / ntile) << 7, bcol = (bid % ntile) << 7;

  const int sru = wave * 8 + (lane >> 3);
  const int scg = (lane & 7) ^ (lane >> 3);
  const int NT = K >> 6;

  f32x4 acc[4][4];
#pragma unroll
  for (int i = 0; i < 4; ++i)
#pragma unroll
    for (int j = 0; j < 4; ++j) acc[i][j] = (f32x4){0.f, 0.f, 0.f, 0.f};

  auto STAGE = [&](int b, int kt) {
    char* base = (char*)smem + b * 32768;
#pragma unroll
    for (int u = 0; u < 2; ++u)
      async_ld16(W + (size_t)(bcol + u * 64 + sru) * K + (size_t)kt * 64 + scg * 8,
                 base + 16384 + u * 8192 + wave * 1024);
#pragma unroll
    for (int u = 0; u < 2; ++u)
      async_ld16(A + (size_t)(brow + u * 64 + sru) * K + (size_t)kt * 64 + scg * 8,
                 base + u * 8192 + wave * 1024);
  };

  const int colb = kg * 64 + g * 16;
  const int swz = (lr & 7) << 4;

  STAGE(0, 0);
  STAGE(1, 1 < NT ? 1 : 0);
  asm volatile("s_waitcnt vmcnt(4)" ::: "memory");
  __builtin_amdgcn_s_barrier();

  for (int t = 0; t < NT; ++t) {
    const int b = t % 3;
    const char* Ab = (const char*)smem + b * 32768;
    const char* Bb = Ab + 16384;

    short8 bf[4], af[4];
#pragma unroll
    for (int nf = 0; nf < 4; ++nf)
      bf[nf] = *(const short8*)(Bb + (wn * 64 + nf * 16 + lr) * 128 +
                                (colb ^ swz));
#pragma unroll
    for (int mf = 0; mf < 2; ++mf) {
      af[mf]     = *(const short8*)(Ab + (wm * 32 + mf * 16 + lr) * 128 +
                                    (colb ^ swz));
      af[mf + 2] = *(const short8*)(Ab + (64 + wm * 32 + mf * 16 + lr) * 128 +
                                    (colb ^ swz));
    }
    {
      const int pt = (t + 2 < NT) ? t + 2 : NT - 1;
      STAGE((t + 2) % 3, pt);
    }
    __builtin_amdgcn_s_setprio(1);
#pragma unroll
    for (int mf = 0; mf < 4; ++mf)
#pragma unroll
      for (int nf = 0; nf < 4; ++nf)
        acc[mf][nf] = __builtin_amdgcn_mfma_f32_16x16x32_bf16(
            af[mf], bf[nf], acc[mf][nf], 0, 0, 0);
    __builtin_amdgcn_s_setprio(0);
    asm volatile("s_waitcnt vmcnt(4)" ::: "memory");
    __builtin_amdgcn_s_barrier();
  }

  asm volatile("s_waitcnt vmcnt(0)" ::: "memory");
  __syncthreads();
  float* pr = (float*)smem + (size_t)((wm << 1) | wn) * 4096;
  if (kg == 1) {
#pragma unroll
    for (int mf = 0; mf < 4; ++mf)
#pragma unroll
      for (int nf = 0; nf < 4; ++nf)
#pragma unroll
        for (int reg = 0; reg < 4; ++reg) {
          const int lrow = mf * 16 + g * 4 + reg;
          const int w = lrow * 64 +
                        ((nf * 16 + lr) ^ (g << 2) ^ ((g & 1) << 4));
          pr[w] = acc[mf][nf][reg];
        }
  }
  __syncthreads();
  if (kg == 0) {
#pragma unroll
    for (int mf = 0; mf < 4; ++mf) {
      const int rb = brow + ((mf < 2) ? wm * 32 + mf * 16
                                      : 64 + wm * 32 + (mf - 2) * 16);
#pragma unroll
      for (int nf = 0; nf < 4; ++nf) {
        const int cI = bcol + wn * 64 + nf * 16 + lr;
        const float bv = bias[cI];
#pragma unroll
        for (int reg = 0; reg < 4; ++reg) {
          const int lrow = mf * 16 + g * 4 + reg;
          const int w = lrow * 64 +
                        ((nf * 16 + lr) ^ (g << 2) ^ ((g & 1) << 4));
          const int r = rb + g * 4 + reg;
          float v = acc[mf][nf][reg] + pr[w] + bv;
          if (GELU_) v = 0.5f * v * (1.0f + erff(v * 0.70710678118654752f));
          if (RESID) v += resid[(size_t)r * N + cI];
          if (OUTBF) ((u16*)out)[(size_t)r * N + cI] = f2bf(v);
          else       ((float*)out)[(size_t)r * N + cI] = v;
        }
      }
    }
  }
}

// ---------------- Flash attention: 8 waves, 128 q-rows/block (r18 best) ---
__global__ __launch_bounds__(512) void attn_kernel(const u16* __restrict__ qkv,
                                                   const u16* __restrict__ vt,
                                                   u16* __restrict__ o_out) {
  const int D = blockIdx.x;
  const int bh = (D & 7) + 8 * (D >> 6);   // same (b,h) -> same XCD
  const int qb = (D >> 3) & 7;
  const int b = bh >> 4, h = bh & 15;
  const int tid = threadIdx.x, wave = tid >> 6, lane = tid & 63;
  const int g = lane >> 4, lr = lane & 15;
  const u16* qg = qkv + (size_t)b * Nn * 3072 + h * 64;
  const u16* kg = qg + 1024;
  const u16* vgt = vt + (size_t)bh * 64 * 1024;

  __shared__ __align__(16) u16 Kl[64 * 64];
  __shared__ __align__(16) u16 Vt[64 * 64];
  __shared__ __align__(16) u16 Pl[128 * 64];

  const int q0 = qb * 128 + wave * 16;
  short8 qf[2];
#pragma unroll
  for (int kf = 0; kf < 2; ++kf)
    qf[kf] = *(const short8*)(qg + (size_t)(q0 + lr) * 3072 + kf * 32 + g * 8);

  f32x4 o[4];
  float ll[4];
#pragma unroll
  for (int df = 0; df < 4; ++df) o[df] = (f32x4){0.f, 0.f, 0.f, 0.f};
#pragma unroll
  for (int r = 0; r < 4; ++r) ll[r] = 0.f;

  const int sc = wave * 64 + lane;             // granule id 0..511
  const int st = sc >> 3;                      // tile row 0..63
  const int sob = ((sc & 7) << 4) ^ ((st & 7) << 4);

  for (int t0 = 0; t0 < Nn; t0 += 64) {
    async_ld16(kg + (size_t)(t0 + st) * 3072 + (sob >> 1),
               (char*)Kl + (size_t)(wave * 64) * 16);
    async_ld16(vgt + (size_t)st * 1024 + t0 + (sob >> 1),
               (char*)Vt + (size_t)(wave * 64) * 16);
    __syncthreads();

    short8 kfr[4][2];
#pragma unroll
    for (int tf = 0; tf < 4; ++tf) {
      const int t = tf * 16 + lr;
#pragma unroll
      for (int kf = 0; kf < 2; ++kf)
        kfr[tf][kf] = *(const short8*)((const char*)Kl + t * 128 +
                                       ((kf * 64 + g * 16) ^ ((t & 7) << 4)));
    }
    f32x4 s[4];
    __builtin_amdgcn_s_setprio(1);
#pragma unroll
    for (int tf = 0; tf < 4; ++tf) {
      f32x4 z = (f32x4){0.f, 0.f, 0.f, 0.f};
      z = __builtin_amdgcn_mfma_f32_16x16x32_bf16(qf[0], kfr[tf][0], z, 0, 0, 0);
      z = __builtin_amdgcn_mfma_f32_16x16x32_bf16(qf[1], kfr[tf][1], z, 0, 0, 0);
      s[tf] = z;
    }
    __builtin_amdgcn_s_setprio(0);

    short8 vfr[4][2];
#pragma unroll
    for (int df = 0; df < 4; ++df) {
      const int d = df * 16 + lr;
#pragma unroll
      for (int kf = 0; kf < 2; ++kf)
        vfr[df][kf] = *(const short8*)((const char*)Vt + d * 128 +
                                       ((kf * 64 + g * 16) ^ ((d & 7) << 4)));
    }

    // no-max softmax (exp safe in fp32 for LN'd inputs); deferred row-reduce
#pragma unroll
    for (int tf = 0; tf < 4; ++tf)
#pragma unroll
      for (int reg = 0; reg < 4; ++reg) {
        const float p = __expf(s[tf][reg] * 0.125f);
        s[tf][reg] = p;
        ll[reg] += p;
      }

#pragma unroll
    for (int tf = 0; tf < 4; ++tf)
#pragma unroll
      for (int reg = 0; reg < 4; ++reg) {
        const int m = wave * 16 + g * 4 + reg;
        const int t2 = (tf * 16 + lr) * 2;
        *(u16*)((char*)Pl + m * 128 + (t2 ^ ((m & 7) << 4))) = f2bf(s[tf][reg]);
      }
    short8 pa[2];
#pragma unroll
    for (int kf = 0; kf < 2; ++kf)
      pa[kf] = *(const short8*)((const char*)Pl + (wave * 16 + lr) * 128 +
                                ((kf * 64 + g * 16) ^ ((lr & 7) << 4)));
    __builtin_amdgcn_s_setprio(1);
#pragma unroll
    for (int df = 0; df < 4; ++df) {
      o[df] = __builtin_amdgcn_mfma_f32_16x16x32_bf16(pa[0], vfr[df][0], o[df], 0, 0, 0);
      o[df] = __builtin_amdgcn_mfma_f32_16x16x32_bf16(pa[1], vfr[df][1], o[df], 0, 0, 0);
    }
    __builtin_amdgcn_s_setprio(0);
    __syncthreads();
  }

#pragma unroll
  for (int reg = 0; reg < 4; ++reg) {
#pragma unroll
    for (int msk = 1; msk < 16; msk <<= 1) ll[reg] += __shfl_xor(ll[reg], msk);
    const float inv = 1.0f / ll[reg];
    const int row = b * Nn + qb * 128 + wave * 16 + g * 4 + reg;
#pragma unroll
    for (int df = 0; df < 4; ++df) {
      const int col = h * 64 + df * 16 + lr;
      o_out[(size_t)row * 1024 + col] = f2bf(o[df][reg] * inv);
    }
  }
}

// ---------------- launch ----------------
extern "C" void kernel_launch(void* const* d_in, const int* in_sizes, int n_in,
                              void* d_out, int out_size, void* d_ws, size_t ws_size,
                              hipStream_t stream) {
  const float* x    = (const float*)d_in[0];
  const float* qkvw = (const float*)d_in[1];
  const float* qkvb = (const float*)d_in[2];
  const float* apw  = (const float*)d_in[3];
  const float* apb  = (const float*)d_in[4];
  const float* bpw  = (const float*)d_in[5];
  const float* bpb  = (const float*)d_in[6];
  const float* ln1g = (const float*)d_in[7];
  const float* ln1b = (const float*)d_in[8];
  const float* ln2g = (const float*)d_in[9];
  const float* ln2b = (const float*)d_in[10];
  const float* fc1w = (const float*)d_in[11];
  const float* fc1b = (const float*)d_in[12];
  const float* fc2w = (const float*)d_in[13];
  const float* fc2b = (const float*)d_in[14];
  float* out = (float*)d_out;

  char* ws = (char*)d_ws;
  size_t off = 0;
  auto alloc = [&](size_t bytes) {
    char* p = ws + off;
    off += (bytes + 255) & ~(size_t)255;
    return p;
  };
  u16* wqkv  = (u16*)alloc((size_t)3145728 * 2);
  u16* wap   = (u16*)alloc((size_t)1048576 * 2);   // hole, never written/read
  u16* wbp   = (u16*)alloc((size_t)1048576 * 2);
  u16* wfc1  = (u16*)alloc((size_t)4194304 * 2);
  u16* wfc2  = (u16*)alloc((size_t)4194304 * 2);
  u16* xn    = (u16*)alloc((size_t)4194304 * 2);
  u16* qkvbf = (u16*)alloc((size_t)12582912 * 2);
  u16* obuf  = (u16*)alloc((size_t)4194304 * 2);
  float* x2  = (float*)alloc((size_t)4194304 * 4);
  u16* wapT  = (u16*)alloc((size_t)1048576 * 2);   // Wap^T bf16
  u16* wc    = (u16*)alloc((size_t)1048576 * 2);   // Wc = Wbp@Wap bf16
  float* cb  = (float*)alloc(1024 * 4);            // combined bias
  u16* vt    = (u16*)alloc((size_t)4194304 * 2);   // V^T per (b,h): [64][1024]
  u16* ff    = qkvbf;
  (void)wap;

  // prep: weight cvt (12288 blks) + Wap^T transpose (256) + cbias (256)
  prep_k<<<12800, 256, 0, stream>>>(qkvw, bpw, fc1w, fc2w, wqkv,
                                    apw, wapT, apb, bpw, bpb, cb);

  // Wc = Wbp @ Wap (256 blks) + LN1 (4096 blks), fused
  g64ln<<<4352, 256, 0, stream>>>(wbp, wapT, wc, x, ln1g, ln1b, xn);

  // qkv = xn @ qkv_w^T + b : Q/K -> qkvbf, V -> vt (transposed, fused)
  gemmS96<<<512, 512, 0, stream>>>(
      xn, wqkv, qkvb, qkvbf, vt, 4096, 3072, 1024);

  attn_kernel<<<512, 512, 0, stream>>>(qkvbf, vt, obuf);

  // x2 = x + obuf @ Wc^T + cb   (fused attn_proj + blk_proj + residual)
  gemm128t<false, true, false><<<256, 512, 0, stream>>>(
      obuf, wc, cb, x, x2, 4096, 1024, 1024);

  ln_bf16<<<4096, 256, 0, stream>>>(x2, ln2g, ln2b, xn);

  // ff = gelu(h @ fc1_w^T + b) : [4096,4096]
  gemmS<true, true><<<512, 512, 0, stream>>>(
      xn, wfc1, fc1b, ff, 4096, 4096, 1024);

  // out = x2 + ff @ fc2_w^T + b  (fp32)
  gemm128t<false, true, false><<<256, 512, 0, stream>>>(
      ff, wfc2, fc2b, x2, out, 4096, 1024, 4096);
}

// Round 25
// 203.218 us; speedup vs baseline: 1.3323x; 1.0196x over previous
//
#include <hip/hip_runtime.h>

typedef unsigned short u16;
typedef __attribute__((ext_vector_type(8))) short short8;
typedef __attribute__((ext_vector_type(4))) float f32x4;

#define DEVI __device__ __forceinline__

static constexpr int Nn = 1024;   // sequence length
static constexpr int Cc = 1024;   // channels

DEVI u16 f2bf(float f) {
  union { float f; unsigned u; } v; v.f = f;
  unsigned r = v.u + 0x7fffu + ((v.u >> 16) & 1u);
  return (u16)(r >> 16);
}

DEVI void async_ld16(const void* g, void* lds) {
  __builtin_amdgcn_global_load_lds(
      (__attribute__((address_space(1))) void*)g,
      (__attribute__((address_space(3))) void*)lds, 16, 0, 0);
}

// -------- fused prep: weight cvt + Wap^T transpose + combined bias + LN1 --
// blocks [0,12288): fp32->bf16 weight convert (skips unused apw hole)
// blocks [12288,12544): transpose apw -> wapT (bf16)
// blocks [12544,12800): cb[j] = bpb[j] + dot(apb, bpw_row_j)
// blocks [12800,16896): LN1 row (B-12800) of x -> xn   (input-only, co-runs)
__global__ __launch_bounds__(256) void prep_k(
    const float* __restrict__ s0, const float* __restrict__ s2,
    const float* __restrict__ s3, const float* __restrict__ s4,
    u16* __restrict__ out,
    const float* __restrict__ apw, u16* __restrict__ wapT,
    const float* __restrict__ apb, const float* __restrict__ bpw,
    const float* __restrict__ bpb, float* __restrict__ cb,
    const float* __restrict__ x, const float* __restrict__ ln1g,
    const float* __restrict__ ln1b, u16* __restrict__ xn) {
  __shared__ u16 tile[64][72];
  __shared__ float ps[4], ps2[4];
  const int B = blockIdx.x;
  const int tid = threadIdx.x;
  if (B < 12288) {
    const size_t j = ((size_t)B * 256 + tid) * 4;
    size_t i; const float* src; size_t lo;
    if (j < 3145728) { i = j; src = s0; lo = 0; }
    else {
      i = j + 1048576;
      if (i < 5242880)      { src = s2; lo = 4194304; }
      else if (i < 9437184) { src = s3; lo = 5242880; }
      else                  { src = s4; lo = 9437184; }
    }
    const float4 v = *(const float4*)&src[i - lo];
    ushort4 o;
    o.x = f2bf(v.x); o.y = f2bf(v.y); o.z = f2bf(v.z); o.w = f2bf(v.w);
    *(ushort4*)&out[i] = o;
  } else if (B < 12544) {
    const int bb = B - 12288;
    const int bx = bb & 15, by = bb >> 4;
    const int tr = tid >> 2;
    const int tc4 = (tid & 3) * 16;
#pragma unroll
    for (int j = 0; j < 4; ++j) {
      const float4 v = *(const float4*)&apw[(size_t)(by * 64 + tr) * 1024 +
                                            bx * 64 + tc4 + j * 4];
      tile[tc4 + j * 4 + 0][tr] = f2bf(v.x);
      tile[tc4 + j * 4 + 1][tr] = f2bf(v.y);
      tile[tc4 + j * 4 + 2][tr] = f2bf(v.z);
      tile[tc4 + j * 4 + 3][tr] = f2bf(v.w);
    }
    __syncthreads();
#pragma unroll
    for (int j = 0; j < 4; ++j) {
      ushort4 o;
      o.x = tile[tr][tc4 + j * 4 + 0];
      o.y = tile[tr][tc4 + j * 4 + 1];
      o.z = tile[tr][tc4 + j * 4 + 2];
      o.w = tile[tr][tc4 + j * 4 + 3];
      *(ushort4*)&wapT[(size_t)(bx * 64 + tr) * 1024 + by * 64 + tc4 + j * 4] = o;
    }
  } else if (B < 12800) {
    const int bb = B - 12544;
    const int j = bb * 4 + (tid >> 6);
    const int lane = tid & 63;
    float s = 0.f;
    for (int k = lane; k < 1024; k += 64) s += apb[k] * bpw[(size_t)j * 1024 + k];
#pragma unroll
    for (int m = 1; m < 64; m <<= 1) s += __shfl_xor(s, m);
    if (lane == 0) cb[j] = s + bpb[j];
  } else {
    const int row = B - 12800;
    const float4 v = ((const float4*)(x + (size_t)row * 1024))[tid];
    float s  = v.x + v.y + v.z + v.w;
    float s2 = v.x * v.x + v.y * v.y + v.z * v.z + v.w * v.w;
#pragma unroll
    for (int m = 1; m < 64; m <<= 1) { s += __shfl_xor(s, m); s2 += __shfl_xor(s2, m); }
    const int wave = tid >> 6;
    if ((tid & 63) == 0) { ps[wave] = s; ps2[wave] = s2; }
    __syncthreads();
    s = ps[0] + ps[1] + ps[2] + ps[3];
    s2 = ps2[0] + ps2[1] + ps2[2] + ps2[3];
    const float mu = s * (1.0f / 1024.0f);
    const float var = s2 * (1.0f / 1024.0f) - mu * mu;
    const float rs = rsqrtf(var + 1e-6f);
    const float4 gv = ((const float4*)ln1g)[tid];
    const float4 bv = ((const float4*)ln1b)[tid];
    ushort4 o;
    o.x = f2bf((v.x - mu) * rs * gv.x + bv.x);
    o.y = f2bf((v.y - mu) * rs * gv.y + bv.y);
    o.z = f2bf((v.z - mu) * rs * gv.z + bv.z);
    o.w = f2bf((v.w - mu) * rs * gv.w + bv.w);
    ((ushort4*)(xn + (size_t)row * 1024))[tid] = o;
  }
}

// ---------------- LayerNorm (row = 1024 fp32) -> bf16 ----------------
__global__ __launch_bounds__(256) void ln_bf16(const float* __restrict__ x,
                                               const float* __restrict__ gg,
                                               const float* __restrict__ bb,
                                               u16* __restrict__ out) {
  const int row = blockIdx.x;
  const float4 v = ((const float4*)(x + (size_t)row * 1024))[threadIdx.x];
  float s  = v.x + v.y + v.z + v.w;
  float s2 = v.x * v.x + v.y * v.y + v.z * v.z + v.w * v.w;
#pragma unroll
  for (int m = 1; m < 64; m <<= 1) { s += __shfl_xor(s, m); s2 += __shfl_xor(s2, m); }
  __shared__ float ps[4], ps2[4];
  const int wave = threadIdx.x >> 6;
  if ((threadIdx.x & 63) == 0) { ps[wave] = s; ps2[wave] = s2; }
  __syncthreads();
  s = ps[0] + ps[1] + ps[2] + ps[3];
  s2 = ps2[0] + ps2[1] + ps2[2] + ps2[3];
  const float mu = s * (1.0f / 1024.0f);
  const float var = s2 * (1.0f / 1024.0f) - mu * mu;
  const float rs = rsqrtf(var + 1e-6f);
  const float4 gv = ((const float4*)gg)[threadIdx.x];
  const float4 bv = ((const float4*)bb)[threadIdx.x];
  ushort4 o;
  o.x = f2bf((v.x - mu) * rs * gv.x + bv.x);
  o.y = f2bf((v.y - mu) * rs * gv.y + bv.y);
  o.z = f2bf((v.z - mu) * rs * gv.z + bv.z);
  o.w = f2bf((v.w - mu) * rs * gv.w + bv.w);
  ((ushort4*)(out + (size_t)row * 1024))[threadIdx.x] = o;
}

// ---------------- GEMM 256x128, BK=64, 8 waves, single-buffer LDS ---------
template <bool GELU_, bool OUTBF>
__global__ __launch_bounds__(512, 4) void gemmS(
    const u16* __restrict__ A, const u16* __restrict__ W,
    const float* __restrict__ bias, void* __restrict__ out,
    int M, int N, int K) {
  __shared__ __align__(16) u16 As[256 * 64];   // 32 KB
  __shared__ __align__(16) u16 Bs[128 * 64];   // 16 KB
  const int tid = threadIdx.x;
  const int wave = tid >> 6, lane = tid & 63;
  const int g = lane >> 4, lr = lane & 15;
  const int wm = wave >> 1, wn = wave & 1;
  const int ntile = N >> 7;
  const int nwg = gridDim.x;
  int bid = blockIdx.x;
  bid = (bid & 7) * (nwg >> 3) + (bid >> 3);   // XCD swizzle (grid % 8 == 0)
  const int brow = (bid / ntile) << 8, bcol = (bid % ntile) << 7;

  const int sru = wave * 8 + (lane >> 3);
  const int scg = (lane & 7) ^ (lane >> 3);
  const int swz = (lr & 7) << 4;

  f32x4 acc[4][4];
#pragma unroll
  for (int i = 0; i < 4; ++i)
#pragma unroll
    for (int j = 0; j < 4; ++j) acc[i][j] = (f32x4){0.f, 0.f, 0.f, 0.f};

  for (int k0 = 0; k0 < K; k0 += 64) {
#pragma unroll
    for (int u = 0; u < 2; ++u)
      async_ld16(W + (size_t)(bcol + u * 64 + sru) * K + k0 + scg * 8,
                 (char*)Bs + u * 8192 + wave * 1024);
#pragma unroll
    for (int u = 0; u < 4; ++u)
      async_ld16(A + (size_t)(brow + u * 64 + sru) * K + k0 + scg * 8,
                 (char*)As + u * 8192 + wave * 1024);
    asm volatile("s_waitcnt vmcnt(0)" ::: "memory");
    __builtin_amdgcn_s_barrier();

    short8 bf[4][2];
#pragma unroll
    for (int nf = 0; nf < 4; ++nf) {
      const int row = wn * 64 + nf * 16 + lr;
#pragma unroll
      for (int kk = 0; kk < 2; ++kk)
        bf[nf][kk] = *(const short8*)((const char*)Bs + row * 128 +
                                      ((kk * 64 + g * 16) ^ swz));
    }
    __builtin_amdgcn_s_setprio(1);
#pragma unroll
    for (int mf = 0; mf < 4; ++mf) {
      short8 af[2];
      const int row = wm * 64 + mf * 16 + lr;
#pragma unroll
      for (int kk = 0; kk < 2; ++kk)
        af[kk] = *(const short8*)((const char*)As + row * 128 +
                                  ((kk * 64 + g * 16) ^ swz));
#pragma unroll
      for (int nf = 0; nf < 4; ++nf)
#pragma unroll
        for (int kk = 0; kk < 2; ++kk)
          acc[mf][nf] = __builtin_amdgcn_mfma_f32_16x16x32_bf16(
              af[kk], bf[nf][kk], acc[mf][nf], 0, 0, 0);
    }
    __builtin_amdgcn_s_setprio(0);
    __builtin_amdgcn_s_barrier();
  }

#pragma unroll
  for (int mf = 0; mf < 4; ++mf)
#pragma unroll
    for (int nf = 0; nf < 4; ++nf) {
      const int cI = bcol + wn * 64 + nf * 16 + lr;
      const float bv = bias[cI];
#pragma unroll
      for (int reg = 0; reg < 4; ++reg) {
        const int r = brow + wm * 64 + mf * 16 + g * 4 + reg;
        float v = acc[mf][nf][reg] + bv;
        if (GELU_) v = 0.5f * v * (1.0f + erff(v * 0.70710678118654752f));
        if (OUTBF) ((u16*)out)[(size_t)r * N + cI] = f2bf(v);
        else       ((float*)out)[(size_t)r * N + cI] = v;
      }
    }
}

// -------- merged qkv launch: gemmS96 (blocks<512) + gemm64 Wc (512..768) --
// qkv: Q/K -> qkvbf, V -> vt transposed (r24-proven).  gemm64 computes
// wc = wbp @ wapT with 4 active waves (waves 4-7 idle but join barriers);
// wc is consumed only by the proj GEMM after attention, so it rides the
// qkv launch's tail for free.
__global__ __launch_bounds__(512, 4) void qkv_k(
    const u16* __restrict__ A, const u16* __restrict__ W,
    const float* __restrict__ bias, u16* __restrict__ out,
    u16* __restrict__ vt,
    const u16* __restrict__ wbp, const u16* __restrict__ wapT,
    u16* __restrict__ wc) {
  __shared__ __align__(16) u16 As[256 * 64];   // 32 KB
  __shared__ __align__(16) u16 Bs[96 * 64];    // 12 KB
  const int tid = threadIdx.x;
  const int wave = tid >> 6, lane = tid & 63;
  const int g = lane >> 4, lr = lane & 15;
  const int swz = (lr & 7) << 4;
  const int M = 4096, N = 3072, K = 1024;

  if (blockIdx.x < 512) {
    const int wm = wave >> 1, wn = wave & 1;   // 4m x 2n -> wave: 64 x 48
    const int ntile = N / 96;                  // 32
    int bid = blockIdx.x;
    bid = (bid & 7) * 64 + (bid >> 3);         // XCD swizzle over 512
    const int brow = (bid / ntile) << 8;
    const int bcol = (bid % ntile) * 96;

    const int sru = wave * 8 + (lane >> 3);
    const int scg = (lane & 7) ^ (lane >> 3);
    const int brG = tid >> 3;
    const int bcg = (tid & 7) ^ (brG & 7);

    f32x4 acc[4][3];
#pragma unroll
    for (int i = 0; i < 4; ++i)
#pragma unroll
      for (int j = 0; j < 3; ++j) acc[i][j] = (f32x4){0.f, 0.f, 0.f, 0.f};

    for (int k0 = 0; k0 < K; k0 += 64) {
      async_ld16(W + (size_t)(bcol + brG) * K + k0 + bcg * 8,
                 (char*)Bs + tid * 16);
      if (wave < 4)
        async_ld16(W + (size_t)(bcol + 64 + brG) * K + k0 + bcg * 8,
                   (char*)Bs + 8192 + tid * 16);
#pragma unroll
      for (int u = 0; u < 4; ++u)
        async_ld16(A + (size_t)(brow + u * 64 + sru) * K + k0 + scg * 8,
                   (char*)As + u * 8192 + wave * 1024);
      asm volatile("s_waitcnt vmcnt(0)" ::: "memory");
      __builtin_amdgcn_s_barrier();

      short8 bf[3][2];
#pragma unroll
      for (int nf = 0; nf < 3; ++nf) {
        const int row = wn * 48 + nf * 16 + lr;
#pragma unroll
        for (int kk = 0; kk < 2; ++kk)
          bf[nf][kk] = *(const short8*)((const char*)Bs + row * 128 +
                                        ((kk * 64 + g * 16) ^ swz));
      }
      __builtin_amdgcn_s_setprio(1);
#pragma unroll
      for (int mf = 0; mf < 4; ++mf) {
        short8 af[2];
        const int row = wm * 64 + mf * 16 + lr;
#pragma unroll
        for (int kk = 0; kk < 2; ++kk)
          af[kk] = *(const short8*)((const char*)As + row * 128 +
                                    ((kk * 64 + g * 16) ^ swz));
#pragma unroll
        for (int nf = 0; nf < 3; ++nf)
#pragma unroll
          for (int kk = 0; kk < 2; ++kk)
            acc[mf][nf] = __builtin_amdgcn_mfma_f32_16x16x32_bf16(
                af[kk], bf[nf][kk], acc[mf][nf], 0, 0, 0);
      }
      __builtin_amdgcn_s_setprio(0);
      __builtin_amdgcn_s_barrier();
    }

#pragma unroll
    for (int nf = 0; nf < 3; ++nf) {
      const int cb0 = bcol + wn * 48 + nf * 16;
      const int cI = cb0 + lr;
      const float bv = bias[cI];
      if (cb0 < 2048) {
#pragma unroll
        for (int mf = 0; mf < 4; ++mf)
#pragma unroll
          for (int reg = 0; reg < 4; ++reg) {
            const int r = brow + wm * 64 + mf * 16 + g * 4 + reg;
            out[(size_t)r * N + cI] = f2bf(acc[mf][nf][reg] + bv);
          }
      } else {
        const int dg0 = cb0 - 2048;
        const int hh = dg0 >> 6;
        const int d = (dg0 & 63) + lr;
#pragma unroll
        for (int mf = 0; mf < 4; ++mf)
#pragma unroll
          for (int reg = 0; reg < 4; ++reg) {
            const int r = brow + wm * 64 + mf * 16 + g * 4 + reg;
            const int b = r >> 10, t = r & 1023;
            vt[(size_t)(((b << 4) + hh) * 64 + d) * 1024 + t] =
                f2bf(acc[mf][nf][reg] + bv);
          }
      }
    }
  } else {
    // gemm64: wc = wbp @ wapT, 64x64 tile, 4 active waves (4-7 idle)
    const int bb = blockIdx.x - 512;
    const int brow = (bb >> 4) << 6, bcol = (bb & 15) << 6;
    const int srow = lane >> 3;
    const int scg = (lane & 7) ^ srow;
    const bool act = wave < 4;

    f32x4 acc[4];
#pragma unroll
    for (int j = 0; j < 4; ++j) acc[j] = (f32x4){0.f, 0.f, 0.f, 0.f};

    for (int k0 = 0; k0 < 1024; k0 += 64) {
      if (act) {
#pragma unroll
        for (int u = 0; u < 2; ++u) {
          async_ld16(wbp + (size_t)(brow + u * 32 + wave * 8 + srow) * 1024 + k0 + scg * 8,
                     (char*)As + u * 4096 + wave * 1024);
          async_ld16(wapT + (size_t)(bcol + u * 32 + wave * 8 + srow) * 1024 + k0 + scg * 8,
                     (char*)Bs + u * 4096 + wave * 1024);
        }
      }
      asm volatile("s_waitcnt vmcnt(0)" ::: "memory");
      __builtin_amdgcn_s_barrier();
      if (act) {
        short8 af[2], bf[4][2];
#pragma unroll
        for (int kk = 0; kk < 2; ++kk)
          af[kk] = *(const short8*)((char*)As + (wave * 16 + lr) * 128 +
                                    ((kk * 64 + g * 16) ^ swz));
#pragma unroll
        for (int nf = 0; nf < 4; ++nf)
#pragma unroll
          for (int kk = 0; kk < 2; ++kk)
            bf[nf][kk] = *(const short8*)((char*)Bs + (nf * 16 + lr) * 128 +
                                          ((kk * 64 + g * 16) ^ swz));
#pragma unroll
        for (int kk = 0; kk < 2; ++kk)
#pragma unroll
          for (int nf = 0; nf < 4; ++nf)
            acc[nf] = __builtin_amdgcn_mfma_f32_16x16x32_bf16(af[kk], bf[nf][kk],
                                                              acc[nf], 0, 0, 0);
      }
      __builtin_amdgcn_s_barrier();
    }
    if (act) {
#pragma unroll
      for (int nf = 0; nf < 4; ++nf)
#pragma unroll
        for (int reg = 0; reg < 4; ++reg)
          wc[(size_t)(brow + wave * 16 + g * 4 + reg) * 1024 +
             bcol + nf * 16 + lr] = f2bf(acc[nf][reg]);
    }
  }
}

// ---------------- GEMM 128x128 TRIPLE-buffer (grid 256 ONLY: L2-resident) -
template <bool GELU_, bool RESID, bool OUTBF>
__global__ __launch_bounds__(512, 2) void gemm128t(
    const u16* __restrict__ A, const u16* __restrict__ W,
    const float* __restrict__ bias, const float* __restrict__ resid,
    void* __restrict__ out, int M, int N, int K) {
  __shared__ __align__(16) u16 smem[49152];   // 96 KB: 3 x (A 16K | B 16K)
  const int tid = threadIdx.x;
  const int wave = tid >> 6, lane = tid & 63;
  const int g = lane >> 4, lr = lane & 15;
  const int kg = wave & 1, ws = wave >> 1;
  const int wm = ws >> 1, wn = ws & 1;
  const int ntile = N >> 7;
  const int nwg = gridDim.x;
  int bid = blockIdx.x;
  bid = (bid & 7) * (nwg >> 3) + (bid >> 3);   // grid % 8 == 0
  const int brow = (bid / ntile) << 7, bcol = (bid % ntile) << 7;

  const int sru = wave * 8 + (lane >> 3);
  const int scg = (lane & 7) ^ (lane >> 3);
  const int NT = K >> 6;

  f32x4 acc[4][4];
#pragma unroll
  for (int i = 0; i < 4; ++i)
#pragma unroll
    for (int j = 0; j < 4; ++j) acc[i][j] = (f32x4){0.f, 0.f, 0.f, 0.f};

  auto STAGE = [&](int b, int kt) {
    char* base = (char*)smem + b * 32768;
#pragma unroll
    for (int u = 0; u < 2; ++u)
      async_ld16(W + (size_t)(bcol + u * 64 + sru) * K + (size_t)kt * 64 + scg * 8,
                 base + 16384 + u * 8192 + wave * 1024);
#pragma unroll
    for (int u = 0; u < 2; ++u)
      async_ld16(A + (size_t)(brow + u * 64 + sru) * K + (size_t)kt * 64 + scg * 8,
                 base + u * 8192 + wave * 1024);
  };

  const int colb = kg * 64 + g * 16;
  const int swz = (lr & 7) << 4;

  STAGE(0, 0);
  STAGE(1, 1 < NT ? 1 : 0);
  asm volatile("s_waitcnt vmcnt(4)" ::: "memory");
  __builtin_amdgcn_s_barrier();

  for (int t = 0; t < NT; ++t) {
    const int b = t % 3;
    const char* Ab = (const char*)smem + b * 32768;
    const char* Bb = Ab + 16384;

    short8 bf[4], af[4];
#pragma unroll
    for (int nf = 0; nf < 4; ++nf)
      bf[nf] = *(const short8*)(Bb + (wn * 64 + nf * 16 + lr) * 128 +
                                (colb ^ swz));
#pragma unroll
    for (int mf = 0; mf < 2; ++mf) {
      af[mf]     = *(const short8*)(Ab + (wm * 32 + mf * 16 + lr) * 128 +
                                    (colb ^ swz));
      af[mf + 2] = *(const short8*)(Ab + (64 + wm * 32 + mf * 16 + lr) * 128 +
                                    (colb ^ swz));
    }
    {
      const int pt = (t + 2 < NT) ? t + 2 : NT - 1;
      STAGE((t + 2) % 3, pt);
    }
    __builtin_amdgcn_s_setprio(1);
#pragma unroll
    for (int mf = 0; mf < 4; ++mf)
#pragma unroll
      for (int nf = 0; nf < 4; ++nf)
        acc[mf][nf] = __builtin_amdgcn_mfma_f32_16x16x32_bf16(
            af[mf], bf[nf], acc[mf][nf], 0, 0, 0);
    __builtin_amdgcn_s_setprio(0);
    asm volatile("s_waitcnt vmcnt(4)" ::: "memory");
    __builtin_amdgcn_s_barrier();
  }

  asm volatile("s_waitcnt vmcnt(0)" ::: "memory");
  __syncthreads();
  float* pr = (float*)smem + (size_t)((wm << 1) | wn) * 4096;
  if (kg == 1) {
#pragma unroll
    for (int mf = 0; mf < 4; ++mf)
#pragma unroll
      for (int nf = 0; nf < 4; ++nf)
#pragma unroll
        for (int reg = 0; reg < 4; ++reg) {
          const int lrow = mf * 16 + g * 4 + reg;
          const int w = lrow * 64 +
                        ((nf * 16 + lr) ^ (g << 2) ^ ((g & 1) << 4));
          pr[w] = acc[mf][nf][reg];
        }
  }
  __syncthreads();
  if (kg == 0) {
#pragma unroll
    for (int mf = 0; mf < 4; ++mf) {
      const int rb = brow + ((mf < 2) ? wm * 32 + mf * 16
                                      : 64 + wm * 32 + (mf - 2) * 16);
#pragma unroll
      for (int nf = 0; nf < 4; ++nf) {
        const int cI = bcol + wn * 64 + nf * 16 + lr;
        const float bv = bias[cI];
#pragma unroll
        for (int reg = 0; reg < 4; ++reg) {
          const int lrow = mf * 16 + g * 4 + reg;
          const int w = lrow * 64 +
                        ((nf * 16 + lr) ^ (g << 2) ^ ((g & 1) << 4));
          const int r = rb + g * 4 + reg;
          float v = acc[mf][nf][reg] + pr[w] + bv;
          if (GELU_) v = 0.5f * v * (1.0f + erff(v * 0.70710678118654752f));
          if (RESID) v += resid[(size_t)r * N + cI];
          if (OUTBF) ((u16*)out)[(size_t)r * N + cI] = f2bf(v);
          else       ((float*)out)[(size_t)r * N + cI] = v;
        }
      }
    }
  }
}

// ---------------- Flash attention: 8 waves, 128 q-rows/block (r18 best) ---
__global__ __launch_bounds__(512) void attn_kernel(const u16* __restrict__ qkv,
                                                   const u16* __restrict__ vt,
                                                   u16* __restrict__ o_out) {
  const int D = blockIdx.x;
  const int bh = (D & 7) + 8 * (D >> 6);   // same (b,h) -> same XCD
  const int qb = (D >> 3) & 7;
  const int b = bh >> 4, h = bh & 15;
  const int tid = threadIdx.x, wave = tid >> 6, lane = tid & 63;
  const int g = lane >> 4, lr = lane & 15;
  const u16* qg = qkv + (size_t)b * Nn * 3072 + h * 64;
  const u16* kg = qg + 1024;
  const u16* vgt = vt + (size_t)bh * 64 * 1024;

  __shared__ __align__(16) u16 Kl[64 * 64];
  __shared__ __align__(16) u16 Vt[64 * 64];
  __shared__ __align__(16) u16 Pl[128 * 64];

  const int q0 = qb * 128 + wave * 16;
  short8 qf[2];
#pragma unroll
  for (int kf = 0; kf < 2; ++kf)
    qf[kf] = *(const short8*)(qg + (size_t)(q0 + lr) * 3072 + kf * 32 + g * 8);

  f32x4 o[4];
  float ll[4];
#pragma unroll
  for (int df = 0; df < 4; ++df) o[df] = (f32x4){0.f, 0.f, 0.f, 0.f};
#pragma unroll
  for (int r = 0; r < 4; ++r) ll[r] = 0.f;

  const int sc = wave * 64 + lane;             // granule id 0..511
  const int st = sc >> 3;                      // tile row 0..63
  const int sob = ((sc & 7) << 4) ^ ((st & 7) << 4);

  for (int t0 = 0; t0 < Nn; t0 += 64) {
    async_ld16(kg + (size_t)(t0 + st) * 3072 + (sob >> 1),
               (char*)Kl + (size_t)(wave * 64) * 16);
    async_ld16(vgt + (size_t)st * 1024 + t0 + (sob >> 1),
               (char*)Vt + (size_t)(wave * 64) * 16);
    __syncthreads();

    short8 kfr[4][2];
#pragma unroll
    for (int tf = 0; tf < 4; ++tf) {
      const int t = tf * 16 + lr;
#pragma unroll
      for (int kf = 0; kf < 2; ++kf)
        kfr[tf][kf] = *(const short8*)((const char*)Kl + t * 128 +
                                       ((kf * 64 + g * 16) ^ ((t & 7) << 4)));
    }
    f32x4 s[4];
    __builtin_amdgcn_s_setprio(1);
#pragma unroll
    for (int tf = 0; tf < 4; ++tf) {
      f32x4 z = (f32x4){0.f, 0.f, 0.f, 0.f};
      z = __builtin_amdgcn_mfma_f32_16x16x32_bf16(qf[0], kfr[tf][0], z, 0, 0, 0);
      z = __builtin_amdgcn_mfma_f32_16x16x32_bf16(qf[1], kfr[tf][1], z, 0, 0, 0);
      s[tf] = z;
    }
    __builtin_amdgcn_s_setprio(0);

    short8 vfr[4][2];
#pragma unroll
    for (int df = 0; df < 4; ++df) {
      const int d = df * 16 + lr;
#pragma unroll
      for (int kf = 0; kf < 2; ++kf)
        vfr[df][kf] = *(const short8*)((const char*)Vt + d * 128 +
                                       ((kf * 64 + g * 16) ^ ((d & 7) << 4)));
    }

    // no-max softmax (exp safe in fp32 for LN'd inputs); deferred row-reduce
#pragma unroll
    for (int tf = 0; tf < 4; ++tf)
#pragma unroll
      for (int reg = 0; reg < 4; ++reg) {
        const float p = __expf(s[tf][reg] * 0.125f);
        s[tf][reg] = p;
        ll[reg] += p;
      }

#pragma unroll
    for (int tf = 0; tf < 4; ++tf)
#pragma unroll
      for (int reg = 0; reg < 4; ++reg) {
        const int m = wave * 16 + g * 4 + reg;
        const int t2 = (tf * 16 + lr) * 2;
        *(u16*)((char*)Pl + m * 128 + (t2 ^ ((m & 7) << 4))) = f2bf(s[tf][reg]);
      }
    short8 pa[2];
#pragma unroll
    for (int kf = 0; kf < 2; ++kf)
      pa[kf] = *(const short8*)((const char*)Pl + (wave * 16 + lr) * 128 +
                                ((kf * 64 + g * 16) ^ ((lr & 7) << 4)));
    __builtin_amdgcn_s_setprio(1);
#pragma unroll
    for (int df = 0; df < 4; ++df) {
      o[df] = __builtin_amdgcn_mfma_f32_16x16x32_bf16(pa[0], vfr[df][0], o[df], 0, 0, 0);
      o[df] = __builtin_amdgcn_mfma_f32_16x16x32_bf16(pa[1], vfr[df][1], o[df], 0, 0, 0);
    }
    __builtin_amdgcn_s_setprio(0);
    __syncthreads();
  }

#pragma unroll
  for (int reg = 0; reg < 4; ++reg) {
#pragma unroll
    for (int msk = 1; msk < 16; msk <<= 1) ll[reg] += __shfl_xor(ll[reg], msk);
    const float inv = 1.0f / ll[reg];
    const int row = b * Nn + qb * 128 + wave * 16 + g * 4 + reg;
#pragma unroll
    for (int df = 0; df < 4; ++df) {
      const int col = h * 64 + df * 16 + lr;
      o_out[(size_t)row * 1024 + col] = f2bf(o[df][reg] * inv);
    }
  }
}

// ---------------- launch ----------------
extern "C" void kernel_launch(void* const* d_in, const int* in_sizes, int n_in,
                              void* d_out, int out_size, void* d_ws, size_t ws_size,
                              hipStream_t stream) {
  const float* x    = (const float*)d_in[0];
  const float* qkvw = (const float*)d_in[1];
  const float* qkvb = (const float*)d_in[2];
  const float* apw  = (const float*)d_in[3];
  const float* apb  = (const float*)d_in[4];
  const float* bpw  = (const float*)d_in[5];
  const float* bpb  = (const float*)d_in[6];
  const float* ln1g = (const float*)d_in[7];
  const float* ln1b = (const float*)d_in[8];
  const float* ln2g = (const float*)d_in[9];
  const float* ln2b = (const float*)d_in[10];
  const float* fc1w = (const float*)d_in[11];
  const float* fc1b = (const float*)d_in[12];
  const float* fc2w = (const float*)d_in[13];
  const float* fc2b = (const float*)d_in[14];
  float* out = (float*)d_out;

  char* ws = (char*)d_ws;
  size_t off = 0;
  auto alloc = [&](size_t bytes) {
    char* p = ws + off;
    off += (bytes + 255) & ~(size_t)255;
    return p;
  };
  u16* wqkv  = (u16*)alloc((size_t)3145728 * 2);
  u16* wap   = (u16*)alloc((size_t)1048576 * 2);   // hole, never written/read
  u16* wbp   = (u16*)alloc((size_t)1048576 * 2);
  u16* wfc1  = (u16*)alloc((size_t)4194304 * 2);
  u16* wfc2  = (u16*)alloc((size_t)4194304 * 2);
  u16* xn    = (u16*)alloc((size_t)4194304 * 2);
  u16* qkvbf = (u16*)alloc((size_t)12582912 * 2);
  u16* obuf  = (u16*)alloc((size_t)4194304 * 2);
  float* x2  = (float*)alloc((size_t)4194304 * 4);
  u16* wapT  = (u16*)alloc((size_t)1048576 * 2);   // Wap^T bf16
  u16* wc    = (u16*)alloc((size_t)1048576 * 2);   // Wc = Wbp@Wap bf16
  float* cb  = (float*)alloc(1024 * 4);            // combined bias
  u16* vt    = (u16*)alloc((size_t)4194304 * 2);   // V^T per (b,h): [64][1024]
  u16* ff    = qkvbf;
  (void)wap;

  // prep: weight cvt + Wap^T transpose + cbias + LN1 (all input-only)
  prep_k<<<16896, 256, 0, stream>>>(qkvw, bpw, fc1w, fc2w, wqkv,
                                    apw, wapT, apb, bpw, bpb, cb,
                                    x, ln1g, ln1b, xn);

  // qkv (512 blks: Q/K->qkvbf, V->vt) + Wc gemm64 (256 blks), one launch
  qkv_k<<<768, 512, 0, stream>>>(xn, wqkv, qkvb, qkvbf, vt, wbp, wapT, wc);

  attn_kernel<<<512, 512, 0, stream>>>(qkvbf, vt, obuf);

  // x2 = x + obuf @ Wc^T + cb   (fused attn_proj + blk_proj + residual)
  gemm128t<false, true, false><<<256, 512, 0, stream>>>(
      obuf, wc, cb, x, x2, 4096, 1024, 1024);

  ln_bf16<<<4096, 256, 0, stream>>>(x2, ln2g, ln2b, xn);

  // ff = gelu(h @ fc1_w^T + b) : [4096,4096]
  gemmS<true, true><<<512, 512, 0, stream>>>(
      xn, wfc1, fc1b, ff, 4096, 4096, 1024);

  // out = x2 + ff @ fc2_w^T + b  (fp32)
  gemm128t<false, true, false><<<256, 512, 0, stream>>>(
      ff, wfc2, fc2b, x2, out, 4096, 1024, 4096);
}